// Round 1
// baseline (3274.033 us; speedup 1.0000x reference)
//
#include <hip/hip_runtime.h>
#include <hip/hip_bf16.h>

#define H 128
#define H4 512
#define BM 16

// ---------------------------------------------------------------- copy x_val -> h (d_out)
__global__ __launch_bounds__(256) void copy_kernel(const float4* __restrict__ src,
                                                   float4* __restrict__ dst, int n4) {
  int i = blockIdx.x * 256 + threadIdx.x;
  int stride = gridDim.x * 256;
  for (; i < n4; i += stride) dst[i] = src[i];
}

// ---------------------------------------------------------------- cst_send MLP + LN(512)
// m[NC,512] = LN( relu(r_cst@W1 + b1) @ W2 ) * g1 + bt1
__global__ __launch_bounds__(256) void cst_mlp_kernel(
    const float* __restrict__ r_cst,
    const float* __restrict__ W1, const float* __restrict__ b1,
    const float* __restrict__ W2, const float* __restrict__ g1,
    const float* __restrict__ bt1, float* __restrict__ m) {
  __shared__ float As[BM][H];    // 8 KB
  __shared__ float Cs[BM][H];    // 8 KB
  __shared__ float Ds[BM][H4];   // 32 KB
  __shared__ float mu_s[BM], rs_s[BM];

  const int tid = threadIdx.x;
  const long row0 = (long)blockIdx.x * BM;

  // stage A tile (16x128)
  {
    const float4* src = (const float4*)(r_cst + row0 * H);
    float4* dst = (float4*)&As[0][0];
#pragma unroll
    for (int i = 0; i < 2; ++i) dst[tid + i * 256] = src[tid + i * 256];
  }
  __syncthreads();

  // phase 1: C = relu(A@W1 + b1). thread -> (col j, 8 rows)
  {
    const int j = tid & (H - 1);
    const int r0 = (tid >> 7) * 8;
    float acc[8] = {0, 0, 0, 0, 0, 0, 0, 0};
#pragma unroll 4
    for (int k = 0; k < H; ++k) {
      float w = W1[k * H + j];
#pragma unroll
      for (int r = 0; r < 8; ++r) acc[r] = fmaf(As[r0 + r][k], w, acc[r]);
    }
    float bb = b1[j];
#pragma unroll
    for (int r = 0; r < 8; ++r) Cs[r0 + r][j] = fmaxf(acc[r] + bb, 0.f);
  }
  __syncthreads();

  // phase 2: D = C@W2. thread -> 2 cols x 16 rows
  {
    const int j = tid * 2;
    float acc[BM][2];
#pragma unroll
    for (int r = 0; r < BM; ++r) acc[r][0] = acc[r][1] = 0.f;
    for (int k = 0; k < H; k += 4) {
      float4 c[BM];
#pragma unroll
      for (int r = 0; r < BM; ++r) c[r] = *(const float4*)&Cs[r][k];
#pragma unroll
      for (int kk = 0; kk < 4; ++kk) {
        const float2 w = *(const float2*)&W2[(k + kk) * H4 + j];
#pragma unroll
        for (int r = 0; r < BM; ++r) {
          float cv = (&c[r].x)[kk];
          acc[r][0] = fmaf(cv, w.x, acc[r][0]);
          acc[r][1] = fmaf(cv, w.y, acc[r][1]);
        }
      }
    }
#pragma unroll
    for (int r = 0; r < BM; ++r) {
      Ds[r][j] = acc[r][0];
      Ds[r][j + 1] = acc[r][1];
    }
  }
  __syncthreads();

  // layernorm stats: wave w handles rows 4w..4w+3
  {
    const int wv = tid >> 6, lane = tid & 63;
    for (int r = wv * 4; r < wv * 4 + 4; ++r) {
      float s = 0.f, q = 0.f;
      const float4* rowp = (const float4*)&Ds[r][0];
#pragma unroll
      for (int i = 0; i < 2; ++i) {
        float4 v = rowp[lane * 2 + i];
        s += v.x + v.y + v.z + v.w;
        q += v.x * v.x + v.y * v.y + v.z * v.z + v.w * v.w;
      }
#pragma unroll
      for (int off = 32; off; off >>= 1) {
        s += __shfl_xor(s, off);
        q += __shfl_xor(q, off);
      }
      if (lane == 0) {
        float mu = s * (1.f / H4);
        float var = q * (1.f / H4) - mu * mu;
        mu_s[r] = mu;
        rs_s[r] = rsqrtf(var + 1e-5f);
      }
    }
  }
  __syncthreads();

  // normalize + affine + store (coalesced float4)
  {
    float4* out4 = (float4*)(m + row0 * H4);
    const float4* D4 = (const float4*)&Ds[0][0];
    const float4* g4 = (const float4*)g1;
    const float4* b4 = (const float4*)bt1;
#pragma unroll
    for (int it = 0; it < 8; ++it) {
      int e4 = tid + it * 256;
      int r = e4 >> 7;   // 128 float4 per row
      int c4 = e4 & 127;
      float4 v = D4[e4];
      float4 g = g4[c4], b = b4[c4];
      float mu = mu_s[r], rs = rs_s[r];
      float4 o;
      o.x = (v.x - mu) * rs * g.x + b.x;
      o.y = (v.y - mu) * rs * g.y + b.y;
      o.z = (v.z - mu) * rs * g.z + b.z;
      o.w = (v.w - mu) * rs * g.w + b.w;
      out4[e4] = o;
    }
  }
}

// ---------------------------------------------------------------- edge scatter-add
// h[c1] += m[4*c0 + 2*LE + PE]; 32 lanes per edge, float4 per lane.
__global__ __launch_bounds__(256) void scatter_kernel(
    const float* __restrict__ m, const int* __restrict__ e_out,
    const int* __restrict__ e_in, const int* __restrict__ LE,
    const int* __restrict__ PE, float* h, int nE) {
  int t = blockIdx.x * 256 + threadIdx.x;
  int edge = t >> 5;
  if (edge >= nE) return;
  int lane = t & 31;
  int c0 = e_out[edge];
  int c1 = e_in[edge];
  int oi = 4 * c0 + 2 * LE[edge] + PE[edge];
  float4 v = *(const float4*)(m + (long)oi * H + lane * 4);
  float* dst = h + (long)c1 * H + lane * 4;
  unsafeAtomicAdd(dst + 0, v.x);
  unsafeAtomicAdd(dst + 1, v.y);
  unsafeAtomicAdd(dst + 2, v.z);
  unsafeAtomicAdd(dst + 3, v.w);
}

// ---------------------------------------------------------------- val_rec MLP + LN(128) + residual
// out[NV,128] = LN( relu(h@W3 + b3) @ W4 ) * g2 + bt2 + x_val   (h == out buffer, in place per block)
__global__ __launch_bounds__(256) void val_mlp_kernel(
    const float* h, const float* __restrict__ x_val,
    const float* __restrict__ W3, const float* __restrict__ b3,
    const float* __restrict__ W4, const float* __restrict__ g2,
    const float* __restrict__ bt2, float* out) {
  __shared__ float As[BM][H];
  __shared__ float Cs[BM][H];
  __shared__ float Ds[BM][H];
  __shared__ float mu_s[BM], rs_s[BM];
  const int tid = threadIdx.x;
  const long row0 = (long)blockIdx.x * BM;

  {
    const float4* src = (const float4*)(h + row0 * H);
    float4* dst = (float4*)&As[0][0];
#pragma unroll
    for (int i = 0; i < 2; ++i) dst[tid + i * 256] = src[tid + i * 256];
  }
  __syncthreads();

  const int j = tid & (H - 1);
  const int r0 = (tid >> 7) * 8;
  {
    float acc[8] = {0, 0, 0, 0, 0, 0, 0, 0};
#pragma unroll 4
    for (int k = 0; k < H; ++k) {
      float w = W3[k * H + j];
#pragma unroll
      for (int r = 0; r < 8; ++r) acc[r] = fmaf(As[r0 + r][k], w, acc[r]);
    }
    float bb = b3[j];
#pragma unroll
    for (int r = 0; r < 8; ++r) Cs[r0 + r][j] = fmaxf(acc[r] + bb, 0.f);
  }
  __syncthreads();
  {
    float acc[8] = {0, 0, 0, 0, 0, 0, 0, 0};
#pragma unroll 4
    for (int k = 0; k < H; ++k) {
      float w = W4[k * H + j];
#pragma unroll
      for (int r = 0; r < 8; ++r) acc[r] = fmaf(Cs[r0 + r][k], w, acc[r]);
    }
#pragma unroll
    for (int r = 0; r < 8; ++r) Ds[r0 + r][j] = acc[r];
  }
  __syncthreads();
  {
    const int wv = tid >> 6, lane = tid & 63;
    for (int r = wv * 4; r < wv * 4 + 4; ++r) {
      float2 v = *(const float2*)&Ds[r][lane * 2];
      float s = v.x + v.y, q = v.x * v.x + v.y * v.y;
#pragma unroll
      for (int off = 32; off; off >>= 1) {
        s += __shfl_xor(s, off);
        q += __shfl_xor(q, off);
      }
      if (lane == 0) {
        float mu = s * (1.f / H);
        mu_s[r] = mu;
        rs_s[r] = rsqrtf(q * (1.f / H) - mu * mu + 1e-5f);
      }
    }
  }
  __syncthreads();
  {
    float4* out4 = (float4*)(out + row0 * H);
    const float4* x4 = (const float4*)(x_val + row0 * H);
    const float4* D4 = (const float4*)&Ds[0][0];
    const float4* g4 = (const float4*)g2;
    const float4* b4 = (const float4*)bt2;
#pragma unroll
    for (int it = 0; it < 2; ++it) {
      int e4 = tid + it * 256;
      int r = e4 >> 5;   // 32 float4 per row
      int c4 = e4 & 31;
      float4 v = D4[e4];
      float4 g = g4[c4], b = b4[c4], xv = x4[e4];
      float mu = mu_s[r], rs = rs_s[r];
      float4 o;
      o.x = (v.x - mu) * rs * g.x + b.x + xv.x;
      o.y = (v.y - mu) * rs * g.y + b.y + xv.y;
      o.z = (v.z - mu) * rs * g.z + b.z + xv.z;
      o.w = (v.w - mu) * rs * g.w + b.w + xv.w;
      out4[e4] = o;
    }
  }
}

extern "C" void kernel_launch(void* const* d_in, const int* in_sizes, int n_in,
                              void* d_out, int out_size, void* d_ws, size_t ws_size,
                              hipStream_t stream) {
  const float* x_val = (const float*)d_in[0];
  const float* r_cst = (const float*)d_in[1];
  const int* edges  = (const int*)d_in[2];   // [2, E]
  const int* LE     = (const int*)d_in[3];
  const int* PE     = (const int*)d_in[4];
  const float* W1  = (const float*)d_in[7];
  const float* b1  = (const float*)d_in[8];
  const float* W2  = (const float*)d_in[9];
  const float* g1  = (const float*)d_in[10];
  const float* bt1 = (const float*)d_in[11];
  const float* W3  = (const float*)d_in[12];
  const float* b3  = (const float*)d_in[13];
  const float* W4  = (const float*)d_in[14];
  const float* g2  = (const float*)d_in[15];
  const float* bt2 = (const float*)d_in[16];

  const int NV = in_sizes[0] / H;
  const int NC = in_sizes[1] / H;
  const int nE = in_sizes[3];

  float* out  = (float*)d_out;
  float* mbuf = (float*)d_ws;  // needs 4*NC*H*4 = 204.8 MB

  // h = x_val (accumulate scatter into d_out, then transform in place)
  copy_kernel<<<2048, 256, 0, stream>>>((const float4*)x_val, (float4*)out, NV * H / 4);

  cst_mlp_kernel<<<NC / BM, 256, 0, stream>>>(r_cst, W1, b1, W2, g1, bt1, mbuf);

  scatter_kernel<<<(nE * 32 + 255) / 256, 256, 0, stream>>>(mbuf, edges, edges + nE, LE, PE,
                                                            out, nE);

  val_mlp_kernel<<<NV / BM, 256, 0, stream>>>(out, x_val, W3, b3, W4, g2, bt2, out);
}

// Round 4
// 854.181 us; speedup vs baseline: 3.8329x; 3.8329x over previous
//
#include <hip/hip_runtime.h>
#include <hip/hip_bf16.h>

#define H 128
#define H4 512
#define BM 16

// ---------------------------------------------------------------- copy (fallback path only)
__global__ __launch_bounds__(256) void copy_kernel(const float4* __restrict__ src,
                                                   float4* __restrict__ dst, int n4) {
  int i = blockIdx.x * 256 + threadIdx.x;
  int stride = gridDim.x * 256;
  for (; i < n4; i += stride) dst[i] = src[i];
}

// ---------------------------------------------------------------- cst_send MLP + LN(512)
__global__ __launch_bounds__(256) void cst_mlp_kernel(
    const float* __restrict__ r_cst,
    const float* __restrict__ W1, const float* __restrict__ b1,
    const float* __restrict__ W2, const float* __restrict__ g1,
    const float* __restrict__ bt1, float* __restrict__ m) {
  __shared__ float As[BM][H];
  __shared__ float Cs[BM][H];
  __shared__ float Ds[BM][H4];
  __shared__ float mu_s[BM], rs_s[BM];

  const int tid = threadIdx.x;
  const long row0 = (long)blockIdx.x * BM;

  {
    const float4* src = (const float4*)(r_cst + row0 * H);
    float4* dst = (float4*)&As[0][0];
#pragma unroll
    for (int i = 0; i < 2; ++i) dst[tid + i * 256] = src[tid + i * 256];
  }
  __syncthreads();

  {
    const int j = tid & (H - 1);
    const int r0 = (tid >> 7) * 8;
    float acc[8] = {0, 0, 0, 0, 0, 0, 0, 0};
#pragma unroll 4
    for (int k = 0; k < H; ++k) {
      float w = W1[k * H + j];
#pragma unroll
      for (int r = 0; r < 8; ++r) acc[r] = fmaf(As[r0 + r][k], w, acc[r]);
    }
    float bb = b1[j];
#pragma unroll
    for (int r = 0; r < 8; ++r) Cs[r0 + r][j] = fmaxf(acc[r] + bb, 0.f);
  }
  __syncthreads();

  {
    const int j = tid * 2;
    float acc[BM][2];
#pragma unroll
    for (int r = 0; r < BM; ++r) acc[r][0] = acc[r][1] = 0.f;
    for (int k = 0; k < H; k += 4) {
      float4 c[BM];
#pragma unroll
      for (int r = 0; r < BM; ++r) c[r] = *(const float4*)&Cs[r][k];
#pragma unroll
      for (int kk = 0; kk < 4; ++kk) {
        const float2 w = *(const float2*)&W2[(k + kk) * H4 + j];
#pragma unroll
        for (int r = 0; r < BM; ++r) {
          float cv = (&c[r].x)[kk];
          acc[r][0] = fmaf(cv, w.x, acc[r][0]);
          acc[r][1] = fmaf(cv, w.y, acc[r][1]);
        }
      }
    }
#pragma unroll
    for (int r = 0; r < BM; ++r) {
      Ds[r][j] = acc[r][0];
      Ds[r][j + 1] = acc[r][1];
    }
  }
  __syncthreads();

  {
    const int wv = tid >> 6, lane = tid & 63;
    for (int r = wv * 4; r < wv * 4 + 4; ++r) {
      float s = 0.f, q = 0.f;
      const float4* rowp = (const float4*)&Ds[r][0];
#pragma unroll
      for (int i = 0; i < 2; ++i) {
        float4 v = rowp[lane * 2 + i];
        s += v.x + v.y + v.z + v.w;
        q += v.x * v.x + v.y * v.y + v.z * v.z + v.w * v.w;
      }
#pragma unroll
      for (int off = 32; off; off >>= 1) {
        s += __shfl_xor(s, off);
        q += __shfl_xor(q, off);
      }
      if (lane == 0) {
        float mu = s * (1.f / H4);
        float var = q * (1.f / H4) - mu * mu;
        mu_s[r] = mu;
        rs_s[r] = rsqrtf(var + 1e-5f);
      }
    }
  }
  __syncthreads();

  {
    float4* out4 = (float4*)(m + row0 * H4);
    const float4* D4 = (const float4*)&Ds[0][0];
    const float4* g4 = (const float4*)g1;
    const float4* b4 = (const float4*)bt1;
#pragma unroll
    for (int it = 0; it < 8; ++it) {
      int e4 = tid + it * 256;
      int r = e4 >> 7;
      int c4 = e4 & 127;
      float4 v = D4[e4];
      float4 g = g4[c4], b = b4[c4];
      float mu = mu_s[r], rs = rs_s[r];
      float4 o;
      o.x = (v.x - mu) * rs * g.x + b.x;
      o.y = (v.y - mu) * rs * g.y + b.y;
      o.z = (v.z - mu) * rs * g.z + b.z;
      o.w = (v.w - mu) * rs * g.w + b.w;
      out4[e4] = o;
    }
  }
}

// ---------------------------------------------------------------- CSR build
__global__ __launch_bounds__(256) void count_kernel(const int* __restrict__ e_in,
                                                    int* __restrict__ cnt, int nE) {
  int i = blockIdx.x * 256 + threadIdx.x;
  if (i < nE) atomicAdd(&cnt[e_in[i]], 1);
}

__device__ inline int wave_incl_scan(int x) {
#pragma unroll
  for (int off = 1; off < 64; off <<= 1) {
    int y = __shfl_up(x, off);
    if ((threadIdx.x & 63) >= off) x += y;
  }
  return x;
}

// per-256-chunk exclusive scan; chunk totals to bsums
__global__ __launch_bounds__(256) void scan1_kernel(const int* __restrict__ cnt,
                                                    int* __restrict__ offs,
                                                    int* __restrict__ bsums, int n) {
  int i = blockIdx.x * 256 + threadIdx.x;
  int v = (i < n) ? cnt[i] : 0;
  int incl = wave_incl_scan(v);
  __shared__ int wsum[4];
  int wv = threadIdx.x >> 6, lane = threadIdx.x & 63;
  if (lane == 63) wsum[wv] = incl;
  __syncthreads();
  int add = 0;
  for (int w = 0; w < wv; ++w) add += wsum[w];
  if (i < n) offs[i] = incl - v + add;
  if (threadIdx.x == 255) bsums[blockIdx.x] = incl + add;
}

// single-block exclusive scan of chunk totals (nb <= 1024)
__global__ __launch_bounds__(1024) void scan2_kernel(int* __restrict__ bsums, int nb,
                                                     int* __restrict__ offs, int n, int total) {
  __shared__ int s[1024];
  int t = threadIdx.x;
  int orig = (t < nb) ? bsums[t] : 0;
  s[t] = orig;
  __syncthreads();
  for (int off = 1; off < 1024; off <<= 1) {
    int v = (t >= off) ? s[t - off] : 0;
    __syncthreads();
    s[t] += v;
    __syncthreads();
  }
  if (t < nb) bsums[t] = s[t] - orig;  // exclusive
  if (t == 0) offs[n] = total;
}

__global__ __launch_bounds__(256) void scan3_kernel(int* __restrict__ offs,
                                                    const int* __restrict__ bsums, int n) {
  int i = blockIdx.x * 256 + threadIdx.x;
  if (i < n) offs[i] += bsums[blockIdx.x];
}

__global__ __launch_bounds__(256) void fill_kernel(
    const int* __restrict__ e_out, const int* __restrict__ e_in,
    const int* __restrict__ LE, const int* __restrict__ PE,
    const int* __restrict__ offs, int* __restrict__ cnt2,
    int* __restrict__ msg_row, int nE) {
  int e = blockIdx.x * 256 + threadIdx.x;
  if (e >= nE) return;
  int v = e_in[e];
  int pos = offs[v] + atomicAdd(&cnt2[v], 1);
  msg_row[pos] = 4 * e_out[e] + 2 * LE[e] + PE[e];
}

// ---------------------------------------------------------------- gather-reduce: h = x_val + sum(msgs)
// one wave per value row; 4 independent row-loads in flight.
__global__ __launch_bounds__(256) void gather_kernel(
    const float* __restrict__ m, const float* __restrict__ x_val,
    const int* __restrict__ offs, const int* __restrict__ msg_row,
    float* __restrict__ h, int nv) {
  int v = blockIdx.x * 4 + (threadIdx.x >> 6);
  if (v >= nv) return;
  int lane = threadIdx.x & 63;
  int beg = offs[v], end = offs[v + 1];
  float2 acc = *(const float2*)(x_val + (long)v * H + lane * 2);
  int p = beg;
  for (; p + 3 < end; p += 4) {
    int r0 = msg_row[p];
    int r1 = msg_row[p + 1];
    int r2 = msg_row[p + 2];
    int r3 = msg_row[p + 3];
    float2 a = *(const float2*)(m + (long)r0 * H + lane * 2);
    float2 b = *(const float2*)(m + (long)r1 * H + lane * 2);
    float2 c = *(const float2*)(m + (long)r2 * H + lane * 2);
    float2 d = *(const float2*)(m + (long)r3 * H + lane * 2);
    acc.x += (a.x + b.x) + (c.x + d.x);
    acc.y += (a.y + b.y) + (c.y + d.y);
  }
  for (; p < end; ++p) {
    int r0 = msg_row[p];
    float2 a = *(const float2*)(m + (long)r0 * H + lane * 2);
    acc.x += a.x;
    acc.y += a.y;
  }
  *(float2*)(h + (long)v * H + lane * 2) = acc;
}

// ---------------------------------------------------------------- fallback atomic scatter
__global__ __launch_bounds__(256) void scatter_kernel(
    const float* __restrict__ m, const int* __restrict__ e_out,
    const int* __restrict__ e_in, const int* __restrict__ LE,
    const int* __restrict__ PE, float* h, int nE) {
  int t = blockIdx.x * 256 + threadIdx.x;
  int edge = t >> 5;
  if (edge >= nE) return;
  int lane = t & 31;
  int c0 = e_out[edge];
  int c1 = e_in[edge];
  int oi = 4 * c0 + 2 * LE[edge] + PE[edge];
  float4 v = *(const float4*)(m + (long)oi * H + lane * 4);
  float* dst = h + (long)c1 * H + lane * 4;
  unsafeAtomicAdd(dst + 0, v.x);
  unsafeAtomicAdd(dst + 1, v.y);
  unsafeAtomicAdd(dst + 2, v.z);
  unsafeAtomicAdd(dst + 3, v.w);
}

// ---------------------------------------------------------------- val_rec MLP + LN(128) + residual
__global__ __launch_bounds__(256) void val_mlp_kernel(
    const float* h, const float* __restrict__ x_val,
    const float* __restrict__ W3, const float* __restrict__ b3,
    const float* __restrict__ W4, const float* __restrict__ g2,
    const float* __restrict__ bt2, float* out) {
  __shared__ float As[BM][H];
  __shared__ float Cs[BM][H];
  __shared__ float Ds[BM][H];
  __shared__ float mu_s[BM], rs_s[BM];
  const int tid = threadIdx.x;
  const long row0 = (long)blockIdx.x * BM;

  {
    const float4* src = (const float4*)(h + row0 * H);
    float4* dst = (float4*)&As[0][0];
#pragma unroll
    for (int i = 0; i < 2; ++i) dst[tid + i * 256] = src[tid + i * 256];
  }
  __syncthreads();

  const int j = tid & (H - 1);
  const int r0 = (tid >> 7) * 8;
  {
    float acc[8] = {0, 0, 0, 0, 0, 0, 0, 0};
#pragma unroll 4
    for (int k = 0; k < H; ++k) {
      float w = W3[k * H + j];
#pragma unroll
      for (int r = 0; r < 8; ++r) acc[r] = fmaf(As[r0 + r][k], w, acc[r]);
    }
    float bb = b3[j];
#pragma unroll
    for (int r = 0; r < 8; ++r) Cs[r0 + r][j] = fmaxf(acc[r] + bb, 0.f);
  }
  __syncthreads();
  {
    float acc[8] = {0, 0, 0, 0, 0, 0, 0, 0};
#pragma unroll 4
    for (int k = 0; k < H; ++k) {
      float w = W4[k * H + j];
#pragma unroll
      for (int r = 0; r < 8; ++r) acc[r] = fmaf(Cs[r0 + r][k], w, acc[r]);
    }
#pragma unroll
    for (int r = 0; r < 8; ++r) Ds[r0 + r][j] = acc[r];
  }
  __syncthreads();
  {
    const int wv = tid >> 6, lane = tid & 63;
    for (int r = wv * 4; r < wv * 4 + 4; ++r) {
      float2 v = *(const float2*)&Ds[r][lane * 2];
      float s = v.x + v.y, q = v.x * v.x + v.y * v.y;
#pragma unroll
      for (int off = 32; off; off >>= 1) {
        s += __shfl_xor(s, off);
        q += __shfl_xor(q, off);
      }
      if (lane == 0) {
        float mu = s * (1.f / H);
        mu_s[r] = mu;
        rs_s[r] = rsqrtf(q * (1.f / H) - mu * mu + 1e-5f);
      }
    }
  }
  __syncthreads();
  {
    float4* out4 = (float4*)(out + row0 * H);
    const float4* x4 = (const float4*)(x_val + row0 * H);
    const float4* D4 = (const float4*)&Ds[0][0];
    const float4* g4 = (const float4*)g2;
    const float4* b4 = (const float4*)bt2;
#pragma unroll
    for (int it = 0; it < 2; ++it) {
      int e4 = tid + it * 256;
      int r = e4 >> 5;
      int c4 = e4 & 31;
      float4 v = D4[e4];
      float4 g = g4[c4], b = b4[c4], xv = x4[e4];
      float mu = mu_s[r], rs = rs_s[r];
      float4 o;
      o.x = (v.x - mu) * rs * g.x + b.x + xv.x;
      o.y = (v.y - mu) * rs * g.y + b.y + xv.y;
      o.z = (v.z - mu) * rs * g.z + b.z + xv.z;
      o.w = (v.w - mu) * rs * g.w + b.w + xv.w;
      out4[e4] = o;
    }
  }
}

extern "C" void kernel_launch(void* const* d_in, const int* in_sizes, int n_in,
                              void* d_out, int out_size, void* d_ws, size_t ws_size,
                              hipStream_t stream) {
  const float* x_val = (const float*)d_in[0];
  const float* r_cst = (const float*)d_in[1];
  const int* edges  = (const int*)d_in[2];   // [2, E]
  const int* LE     = (const int*)d_in[3];
  const int* PE     = (const int*)d_in[4];
  const float* W1  = (const float*)d_in[7];
  const float* b1  = (const float*)d_in[8];
  const float* W2  = (const float*)d_in[9];
  const float* g1  = (const float*)d_in[10];
  const float* bt1 = (const float*)d_in[11];
  const float* W3  = (const float*)d_in[12];
  const float* b3  = (const float*)d_in[13];
  const float* W4  = (const float*)d_in[14];
  const float* g2  = (const float*)d_in[15];
  const float* bt2 = (const float*)d_in[16];

  const int NV = in_sizes[0] / H;
  const int NC = in_sizes[1] / H;
  const int nE = in_sizes[3];

  float* out  = (float*)d_out;
  float* mbuf = (float*)d_ws;                         // 4*NC*H floats

  const size_t mbytes = (size_t)4 * NC * H * sizeof(float);
  int* offs  = (int*)((char*)d_ws + mbytes);          // NV+1
  int* cnt   = offs + (NV + 1);                       // NV
  int* cnt2  = cnt + NV;                              // NV
  int* bsums = cnt2 + NV;                             // up to 1024
  int* msg_row = bsums + 1024;                        // nE
  const size_t need = mbytes + ((size_t)(NV + 1) + NV + NV + 1024 + nE) * sizeof(int);

  const int nb = (NV + 255) / 256;  // scan chunks (must be <= 1024)

  // cst_send MLP first (gather needs mbuf)
  cst_mlp_kernel<<<NC / BM, 256, 0, stream>>>(r_cst, W1, b1, W2, g1, bt1, mbuf);

  if (ws_size >= need && nb <= 1024) {
    // CSR build (stream-serialized, all cheap)
    hipMemsetAsync(cnt, 0, (size_t)NV * sizeof(int), stream);
    hipMemsetAsync(cnt2, 0, (size_t)NV * sizeof(int), stream);
    count_kernel<<<(nE + 255) / 256, 256, 0, stream>>>(edges + nE, cnt, nE);
    scan1_kernel<<<nb, 256, 0, stream>>>(cnt, offs, bsums, NV);
    scan2_kernel<<<1, 1024, 0, stream>>>(bsums, nb, offs, NV, nE);
    scan3_kernel<<<nb, 256, 0, stream>>>(offs, bsums, NV);
    fill_kernel<<<(nE + 255) / 256, 256, 0, stream>>>(edges, edges + nE, LE, PE, offs, cnt2,
                                                      msg_row, nE);
    gather_kernel<<<(NV + 3) / 4, 256, 0, stream>>>(mbuf, x_val, offs, msg_row, out, NV);
  } else {
    // fallback: atomic scatter path
    copy_kernel<<<2048, 256, 0, stream>>>((const float4*)x_val, (float4*)out, NV * H / 4);
    scatter_kernel<<<(nE * 32 + 255) / 256, 256, 0, stream>>>(mbuf, edges, edges + nE, LE, PE,
                                                              out, nE);
  }

  val_mlp_kernel<<<NV / BM, 256, 0, stream>>>(out, x_val, W3, b3, W4, g2, bt2, out);
}

// Round 5
// 658.294 us; speedup vs baseline: 4.9735x; 1.2976x over previous
//
#include <hip/hip_runtime.h>
#include <hip/hip_bf16.h>

#define H 128
#define H4 512
#define BM 16

typedef __bf16 bf16x8 __attribute__((ext_vector_type(8)));
typedef float f32x4 __attribute__((ext_vector_type(4)));

__device__ inline f32x4 mfma16(bf16x8 a, bf16x8 b, f32x4 c) {
  return __builtin_amdgcn_mfma_f32_16x16x32_bf16(a, b, c, 0, 0, 0);
}

// ---------------------------------------------------------------- weight pack: fp32 [K][N] -> hi/lo bf16 MFMA B-fragments
// frag layout: tile = nt*(K/32)+kt ; lane l holds B[kt*32+(l>>4)*8 + i][nt*16+(l&15)], i=0..7
__global__ __launch_bounds__(256) void pack_kernel(const float* __restrict__ W, int K, int N,
                                                   __bf16* __restrict__ hi,
                                                   __bf16* __restrict__ lo) {
  int idx = blockIdx.x * 256 + threadIdx.x;
  int total = (N >> 4) * (K >> 5) * 64;
  if (idx >= total) return;
  int lane = idx & 63;
  int tile = idx >> 6;
  int KT = K >> 5;
  int nt = tile / KT, kt = tile - nt * KT;
  int col = nt * 16 + (lane & 15);
  int k0 = kt * 32 + (lane >> 4) * 8;
#pragma unroll
  for (int i = 0; i < 8; ++i) {
    float x = W[(long)(k0 + i) * N + col];
    __bf16 h = (__bf16)x;
    hi[(long)idx * 8 + i] = h;
    lo[(long)idx * 8 + i] = (__bf16)(x - (float)h);
  }
}

// ---------------------------------------------------------------- copy (fallback path only)
__global__ __launch_bounds__(256) void copy_kernel(const float4* __restrict__ src,
                                                   float4* __restrict__ dst, int n4) {
  int i = blockIdx.x * 256 + threadIdx.x;
  int stride = gridDim.x * 256;
  for (; i < n4; i += stride) dst[i] = src[i];
}

// ---------------------------------------------------------------- cst_send MLP + LN(512), MFMA split-bf16
__global__ __launch_bounds__(256) void cst_mlp_mfma(
    const float* __restrict__ r_cst,
    const __bf16* __restrict__ W1h, const __bf16* __restrict__ W1l,
    const float* __restrict__ b1,
    const __bf16* __restrict__ W2h, const __bf16* __restrict__ W2l,
    const float* __restrict__ g1, const float* __restrict__ bt1,
    float* __restrict__ m) {
  __shared__ float As[BM][132];   // +4 pad: frag-read conflicts 16->8 way
  __shared__ float Cs[BM][132];
  __shared__ float Ds[BM][H4];
  __shared__ float mu_s[BM], rs_s[BM];

  const int tid = threadIdx.x;
  const int wave = tid >> 6, lane = tid & 63;
  const long row0 = (long)blockIdx.x * BM;

  // stage A (16x128)
  {
    const float4* src = (const float4*)(r_cst + row0 * H);
#pragma unroll
    for (int i = 0; i < 2; ++i) {
      int idx = tid + i * 256;            // 0..511 float4s
      int r = idx >> 5, c4 = idx & 31;
      *(float4*)&As[r][c4 * 4] = src[idx];
    }
  }
  __syncthreads();

  const int fr = lane & 15;          // frag M/N index
  const int fk = (lane >> 4) * 8;    // frag k offset
  const int rowb = (lane >> 4) * 4;  // C/D row base

  // A fragments (hi/lo split), all 4 k-tiles
  bf16x8 a_hi[4], a_lo[4];
#pragma unroll
  for (int kt = 0; kt < 4; ++kt) {
    const float* p = &As[fr][kt * 32 + fk];
    float4 u = *(const float4*)p, v = *(const float4*)(p + 4);
    float vals[8] = {u.x, u.y, u.z, u.w, v.x, v.y, v.z, v.w};
#pragma unroll
    for (int i = 0; i < 8; ++i) {
      __bf16 hh = (__bf16)vals[i];
      a_hi[kt][i] = hh;
      a_lo[kt][i] = (__bf16)(vals[i] - (float)hh);
    }
  }

  // GEMM1: C = relu(A@W1 + b1); wave handles n-tiles {2w, 2w+1}
#pragma unroll
  for (int t = 0; t < 2; ++t) {
    const int nt = wave * 2 + t;
    f32x4 acc = {0.f, 0.f, 0.f, 0.f};
#pragma unroll
    for (int kt = 0; kt < 4; ++kt) {
      const long fi = (long)((nt * 4 + kt) * 64 + lane) * 8;
      bf16x8 bh = *(const bf16x8*)(W1h + fi);
      bf16x8 bl = *(const bf16x8*)(W1l + fi);
      acc = mfma16(a_hi[kt], bh, acc);
      acc = mfma16(a_lo[kt], bh, acc);
      acc = mfma16(a_hi[kt], bl, acc);
    }
    const int col = nt * 16 + fr;
    const float bb = b1[col];
#pragma unroll
    for (int r = 0; r < 4; ++r) Cs[rowb + r][col] = fmaxf(acc[r] + bb, 0.f);
  }
  __syncthreads();

  // C fragments
  bf16x8 c_hi[4], c_lo[4];
#pragma unroll
  for (int kt = 0; kt < 4; ++kt) {
    const float* p = &Cs[fr][kt * 32 + fk];
    float4 u = *(const float4*)p, v = *(const float4*)(p + 4);
    float vals[8] = {u.x, u.y, u.z, u.w, v.x, v.y, v.z, v.w};
#pragma unroll
    for (int i = 0; i < 8; ++i) {
      __bf16 hh = (__bf16)vals[i];
      c_hi[kt][i] = hh;
      c_lo[kt][i] = (__bf16)(vals[i] - (float)hh);
    }
  }

  // GEMM2: D = C@W2; wave handles n-tiles {8w..8w+7}
#pragma unroll
  for (int t = 0; t < 8; ++t) {
    const int nt = wave * 8 + t;
    f32x4 acc = {0.f, 0.f, 0.f, 0.f};
#pragma unroll
    for (int kt = 0; kt < 4; ++kt) {
      const long fi = (long)((nt * 4 + kt) * 64 + lane) * 8;
      bf16x8 bh = *(const bf16x8*)(W2h + fi);
      bf16x8 bl = *(const bf16x8*)(W2l + fi);
      acc = mfma16(c_hi[kt], bh, acc);
      acc = mfma16(c_lo[kt], bh, acc);
      acc = mfma16(c_hi[kt], bl, acc);
    }
    const int col = nt * 16 + fr;
#pragma unroll
    for (int r = 0; r < 4; ++r) Ds[rowb + r][col] = acc[r];
  }
  __syncthreads();

  // LN(512) stats
  {
    for (int r = wave * 4; r < wave * 4 + 4; ++r) {
      float s = 0.f, q = 0.f;
      const float4* rowp = (const float4*)&Ds[r][0];
#pragma unroll
      for (int i = 0; i < 2; ++i) {
        float4 v = rowp[lane * 2 + i];
        s += v.x + v.y + v.z + v.w;
        q += v.x * v.x + v.y * v.y + v.z * v.z + v.w * v.w;
      }
#pragma unroll
      for (int off = 32; off; off >>= 1) {
        s += __shfl_xor(s, off);
        q += __shfl_xor(q, off);
      }
      if (lane == 0) {
        float mu = s * (1.f / H4);
        mu_s[r] = mu;
        rs_s[r] = rsqrtf(q * (1.f / H4) - mu * mu + 1e-5f);
      }
    }
  }
  __syncthreads();

  // normalize + affine + store
  {
    float4* out4 = (float4*)(m + row0 * H4);
    const float4* D4 = (const float4*)&Ds[0][0];
    const float4* g4 = (const float4*)g1;
    const float4* b4 = (const float4*)bt1;
#pragma unroll
    for (int it = 0; it < 8; ++it) {
      int e4 = tid + it * 256;
      int r = e4 >> 7;
      int c4 = e4 & 127;
      float4 v = D4[e4];
      float4 g = g4[c4], b = b4[c4];
      float mu = mu_s[r], rs = rs_s[r];
      float4 o;
      o.x = (v.x - mu) * rs * g.x + b.x;
      o.y = (v.y - mu) * rs * g.y + b.y;
      o.z = (v.z - mu) * rs * g.z + b.z;
      o.w = (v.w - mu) * rs * g.w + b.w;
      out4[e4] = o;
    }
  }
}

// ---------------------------------------------------------------- val_rec MLP + LN(128) + residual, MFMA split-bf16
__global__ __launch_bounds__(256) void val_mlp_mfma(
    const float* h, const float* __restrict__ x_val,
    const __bf16* __restrict__ W3h, const __bf16* __restrict__ W3l,
    const float* __restrict__ b3,
    const __bf16* __restrict__ W4h, const __bf16* __restrict__ W4l,
    const float* __restrict__ g2, const float* __restrict__ bt2,
    float* out) {
  __shared__ float As[BM][132];
  __shared__ float Cs[BM][132];
  __shared__ float Ds[BM][H];
  __shared__ float mu_s[BM], rs_s[BM];

  const int tid = threadIdx.x;
  const int wave = tid >> 6, lane = tid & 63;
  const long row0 = (long)blockIdx.x * BM;

  {
    const float4* src = (const float4*)(h + row0 * H);
#pragma unroll
    for (int i = 0; i < 2; ++i) {
      int idx = tid + i * 256;
      int r = idx >> 5, c4 = idx & 31;
      *(float4*)&As[r][c4 * 4] = src[idx];
    }
  }
  __syncthreads();

  const int fr = lane & 15;
  const int fk = (lane >> 4) * 8;
  const int rowb = (lane >> 4) * 4;

  bf16x8 a_hi[4], a_lo[4];
#pragma unroll
  for (int kt = 0; kt < 4; ++kt) {
    const float* p = &As[fr][kt * 32 + fk];
    float4 u = *(const float4*)p, v = *(const float4*)(p + 4);
    float vals[8] = {u.x, u.y, u.z, u.w, v.x, v.y, v.z, v.w};
#pragma unroll
    for (int i = 0; i < 8; ++i) {
      __bf16 hh = (__bf16)vals[i];
      a_hi[kt][i] = hh;
      a_lo[kt][i] = (__bf16)(vals[i] - (float)hh);
    }
  }

#pragma unroll
  for (int t = 0; t < 2; ++t) {
    const int nt = wave * 2 + t;
    f32x4 acc = {0.f, 0.f, 0.f, 0.f};
#pragma unroll
    for (int kt = 0; kt < 4; ++kt) {
      const long fi = (long)((nt * 4 + kt) * 64 + lane) * 8;
      bf16x8 bh = *(const bf16x8*)(W3h + fi);
      bf16x8 bl = *(const bf16x8*)(W3l + fi);
      acc = mfma16(a_hi[kt], bh, acc);
      acc = mfma16(a_lo[kt], bh, acc);
      acc = mfma16(a_hi[kt], bl, acc);
    }
    const int col = nt * 16 + fr;
    const float bb = b3[col];
#pragma unroll
    for (int r = 0; r < 4; ++r) Cs[rowb + r][col] = fmaxf(acc[r] + bb, 0.f);
  }
  __syncthreads();

  bf16x8 c_hi[4], c_lo[4];
#pragma unroll
  for (int kt = 0; kt < 4; ++kt) {
    const float* p = &Cs[fr][kt * 32 + fk];
    float4 u = *(const float4*)p, v = *(const float4*)(p + 4);
    float vals[8] = {u.x, u.y, u.z, u.w, v.x, v.y, v.z, v.w};
#pragma unroll
    for (int i = 0; i < 8; ++i) {
      __bf16 hh = (__bf16)vals[i];
      c_hi[kt][i] = hh;
      c_lo[kt][i] = (__bf16)(vals[i] - (float)hh);
    }
  }

#pragma unroll
  for (int t = 0; t < 2; ++t) {
    const int nt = wave * 2 + t;
    f32x4 acc = {0.f, 0.f, 0.f, 0.f};
#pragma unroll
    for (int kt = 0; kt < 4; ++kt) {
      const long fi = (long)((nt * 4 + kt) * 64 + lane) * 8;
      bf16x8 bh = *(const bf16x8*)(W4h + fi);
      bf16x8 bl = *(const bf16x8*)(W4l + fi);
      acc = mfma16(c_hi[kt], bh, acc);
      acc = mfma16(c_lo[kt], bh, acc);
      acc = mfma16(c_hi[kt], bl, acc);
    }
    const int col = nt * 16 + fr;
#pragma unroll
    for (int r = 0; r < 4; ++r) Ds[rowb + r][col] = acc[r];
  }
  __syncthreads();

  {
    for (int r = wave * 4; r < wave * 4 + 4; ++r) {
      float2 v = *(const float2*)&Ds[r][lane * 2];
      float s = v.x + v.y, q = v.x * v.x + v.y * v.y;
#pragma unroll
      for (int off = 32; off; off >>= 1) {
        s += __shfl_xor(s, off);
        q += __shfl_xor(q, off);
      }
      if (lane == 0) {
        float mu = s * (1.f / H);
        mu_s[r] = mu;
        rs_s[r] = rsqrtf(q * (1.f / H) - mu * mu + 1e-5f);
      }
    }
  }
  __syncthreads();

  {
    float4* out4 = (float4*)(out + row0 * H);
    const float4* x4 = (const float4*)(x_val + row0 * H);
    const float4* D4 = (const float4*)&Ds[0][0];
    const float4* g4 = (const float4*)g2;
    const float4* b4 = (const float4*)bt2;
#pragma unroll
    for (int it = 0; it < 2; ++it) {
      int e4 = tid + it * 256;
      int r = e4 >> 5;
      int c4 = e4 & 31;
      float4 v = D4[e4];
      float4 g = g4[c4], b = b4[c4], xv = x4[e4];
      float mu = mu_s[r], rs = rs_s[r];
      float4 o;
      o.x = (v.x - mu) * rs * g.x + b.x + xv.x;
      o.y = (v.y - mu) * rs * g.y + b.y + xv.y;
      o.z = (v.z - mu) * rs * g.z + b.z + xv.z;
      o.w = (v.w - mu) * rs * g.w + b.w + xv.w;
      out4[e4] = o;
    }
  }
}

// ---------------------------------------------------------------- fp32 fallback MLPs (kept for ws-too-small path)
__global__ __launch_bounds__(256) void cst_mlp_kernel(
    const float* __restrict__ r_cst,
    const float* __restrict__ W1, const float* __restrict__ b1,
    const float* __restrict__ W2, const float* __restrict__ g1,
    const float* __restrict__ bt1, float* __restrict__ m) {
  __shared__ float As[BM][H];
  __shared__ float Cs[BM][H];
  __shared__ float Ds[BM][H4];
  __shared__ float mu_s[BM], rs_s[BM];
  const int tid = threadIdx.x;
  const long row0 = (long)blockIdx.x * BM;
  {
    const float4* src = (const float4*)(r_cst + row0 * H);
    float4* dst = (float4*)&As[0][0];
#pragma unroll
    for (int i = 0; i < 2; ++i) dst[tid + i * 256] = src[tid + i * 256];
  }
  __syncthreads();
  {
    const int j = tid & (H - 1);
    const int r0 = (tid >> 7) * 8;
    float acc[8] = {0, 0, 0, 0, 0, 0, 0, 0};
#pragma unroll 4
    for (int k = 0; k < H; ++k) {
      float w = W1[k * H + j];
#pragma unroll
      for (int r = 0; r < 8; ++r) acc[r] = fmaf(As[r0 + r][k], w, acc[r]);
    }
    float bb = b1[j];
#pragma unroll
    for (int r = 0; r < 8; ++r) Cs[r0 + r][j] = fmaxf(acc[r] + bb, 0.f);
  }
  __syncthreads();
  {
    const int j = tid * 2;
    float acc[BM][2];
#pragma unroll
    for (int r = 0; r < BM; ++r) acc[r][0] = acc[r][1] = 0.f;
    for (int k = 0; k < H; k += 4) {
      float4 c[BM];
#pragma unroll
      for (int r = 0; r < BM; ++r) c[r] = *(const float4*)&Cs[r][k];
#pragma unroll
      for (int kk = 0; kk < 4; ++kk) {
        const float2 w = *(const float2*)&W2[(k + kk) * H4 + j];
#pragma unroll
        for (int r = 0; r < BM; ++r) {
          float cv = (&c[r].x)[kk];
          acc[r][0] = fmaf(cv, w.x, acc[r][0]);
          acc[r][1] = fmaf(cv, w.y, acc[r][1]);
        }
      }
    }
#pragma unroll
    for (int r = 0; r < BM; ++r) {
      Ds[r][j] = acc[r][0];
      Ds[r][j + 1] = acc[r][1];
    }
  }
  __syncthreads();
  {
    const int wv = tid >> 6, lane = tid & 63;
    for (int r = wv * 4; r < wv * 4 + 4; ++r) {
      float s = 0.f, q = 0.f;
      const float4* rowp = (const float4*)&Ds[r][0];
#pragma unroll
      for (int i = 0; i < 2; ++i) {
        float4 v = rowp[lane * 2 + i];
        s += v.x + v.y + v.z + v.w;
        q += v.x * v.x + v.y * v.y + v.z * v.z + v.w * v.w;
      }
#pragma unroll
      for (int off = 32; off; off >>= 1) {
        s += __shfl_xor(s, off);
        q += __shfl_xor(q, off);
      }
      if (lane == 0) {
        float mu = s * (1.f / H4);
        mu_s[r] = mu;
        rs_s[r] = rsqrtf(q * (1.f / H4) - mu * mu + 1e-5f);
      }
    }
  }
  __syncthreads();
  {
    float4* out4 = (float4*)(m + row0 * H4);
    const float4* D4 = (const float4*)&Ds[0][0];
    const float4* g4 = (const float4*)g1;
    const float4* b4 = (const float4*)bt1;
#pragma unroll
    for (int it = 0; it < 8; ++it) {
      int e4 = tid + it * 256;
      int r = e4 >> 7;
      int c4 = e4 & 127;
      float4 v = D4[e4];
      float4 g = g4[c4], b = b4[c4];
      float mu = mu_s[r], rs = rs_s[r];
      float4 o;
      o.x = (v.x - mu) * rs * g.x + b.x;
      o.y = (v.y - mu) * rs * g.y + b.y;
      o.z = (v.z - mu) * rs * g.z + b.z;
      o.w = (v.w - mu) * rs * g.w + b.w;
      out4[e4] = o;
    }
  }
}

__global__ __launch_bounds__(256) void val_mlp_kernel(
    const float* h, const float* __restrict__ x_val,
    const float* __restrict__ W3, const float* __restrict__ b3,
    const float* __restrict__ W4, const float* __restrict__ g2,
    const float* __restrict__ bt2, float* out) {
  __shared__ float As[BM][H];
  __shared__ float Cs[BM][H];
  __shared__ float Ds[BM][H];
  __shared__ float mu_s[BM], rs_s[BM];
  const int tid = threadIdx.x;
  const long row0 = (long)blockIdx.x * BM;
  {
    const float4* src = (const float4*)(h + row0 * H);
    float4* dst = (float4*)&As[0][0];
#pragma unroll
    for (int i = 0; i < 2; ++i) dst[tid + i * 256] = src[tid + i * 256];
  }
  __syncthreads();
  const int j = tid & (H - 1);
  const int r0 = (tid >> 7) * 8;
  {
    float acc[8] = {0, 0, 0, 0, 0, 0, 0, 0};
#pragma unroll 4
    for (int k = 0; k < H; ++k) {
      float w = W3[k * H + j];
#pragma unroll
      for (int r = 0; r < 8; ++r) acc[r] = fmaf(As[r0 + r][k], w, acc[r]);
    }
    float bb = b3[j];
#pragma unroll
    for (int r = 0; r < 8; ++r) Cs[r0 + r][j] = fmaxf(acc[r] + bb, 0.f);
  }
  __syncthreads();
  {
    float acc[8] = {0, 0, 0, 0, 0, 0, 0, 0};
#pragma unroll 4
    for (int k = 0; k < H; ++k) {
      float w = W4[k * H + j];
#pragma unroll
      for (int r = 0; r < 8; ++r) acc[r] = fmaf(Cs[r0 + r][k], w, acc[r]);
    }
#pragma unroll
    for (int r = 0; r < 8; ++r) Ds[r0 + r][j] = acc[r];
  }
  __syncthreads();
  {
    const int wv = tid >> 6, lane = tid & 63;
    for (int r = wv * 4; r < wv * 4 + 4; ++r) {
      float2 v = *(const float2*)&Ds[r][lane * 2];
      float s = v.x + v.y, q = v.x * v.x + v.y * v.y;
#pragma unroll
      for (int off = 32; off; off >>= 1) {
        s += __shfl_xor(s, off);
        q += __shfl_xor(q, off);
      }
      if (lane == 0) {
        float mu = s * (1.f / H);
        mu_s[r] = mu;
        rs_s[r] = rsqrtf(q * (1.f / H) - mu * mu + 1e-5f);
      }
    }
  }
  __syncthreads();
  {
    float4* out4 = (float4*)(out + row0 * H);
    const float4* x4 = (const float4*)(x_val + row0 * H);
    const float4* D4 = (const float4*)&Ds[0][0];
    const float4* g4 = (const float4*)g2;
    const float4* b4 = (const float4*)bt2;
#pragma unroll
    for (int it = 0; it < 2; ++it) {
      int e4 = tid + it * 256;
      int r = e4 >> 5;
      int c4 = e4 & 31;
      float4 v = D4[e4];
      float4 g = g4[c4], b = b4[c4], xv = x4[e4];
      float mu = mu_s[r], rs = rs_s[r];
      float4 o;
      o.x = (v.x - mu) * rs * g.x + b.x + xv.x;
      o.y = (v.y - mu) * rs * g.y + b.y + xv.y;
      o.z = (v.z - mu) * rs * g.z + b.z + xv.z;
      o.w = (v.w - mu) * rs * g.w + b.w + xv.w;
      out4[e4] = o;
    }
  }
}

// ---------------------------------------------------------------- CSR build
__global__ __launch_bounds__(256) void count_kernel(const int* __restrict__ e_in,
                                                    int* __restrict__ cnt, int nE) {
  int i = blockIdx.x * 256 + threadIdx.x;
  if (i < nE) atomicAdd(&cnt[e_in[i]], 1);
}

__device__ inline int wave_incl_scan(int x) {
#pragma unroll
  for (int off = 1; off < 64; off <<= 1) {
    int y = __shfl_up(x, off);
    if ((threadIdx.x & 63) >= off) x += y;
  }
  return x;
}

__global__ __launch_bounds__(256) void scan1_kernel(const int* __restrict__ cnt,
                                                    int* __restrict__ offs,
                                                    int* __restrict__ bsums, int n) {
  int i = blockIdx.x * 256 + threadIdx.x;
  int v = (i < n) ? cnt[i] : 0;
  int incl = wave_incl_scan(v);
  __shared__ int wsum[4];
  int wv = threadIdx.x >> 6, lane = threadIdx.x & 63;
  if (lane == 63) wsum[wv] = incl;
  __syncthreads();
  int add = 0;
  for (int w = 0; w < wv; ++w) add += wsum[w];
  if (i < n) offs[i] = incl - v + add;
  if (threadIdx.x == 255) bsums[blockIdx.x] = incl + add;
}

__global__ __launch_bounds__(1024) void scan2_kernel(int* __restrict__ bsums, int nb,
                                                     int* __restrict__ offs, int n, int total) {
  __shared__ int s[1024];
  int t = threadIdx.x;
  int orig = (t < nb) ? bsums[t] : 0;
  s[t] = orig;
  __syncthreads();
  for (int off = 1; off < 1024; off <<= 1) {
    int v = (t >= off) ? s[t - off] : 0;
    __syncthreads();
    s[t] += v;
    __syncthreads();
  }
  if (t < nb) bsums[t] = s[t] - orig;
  if (t == 0) offs[n] = total;
}

__global__ __launch_bounds__(256) void scan3_kernel(int* __restrict__ offs,
                                                    const int* __restrict__ bsums, int n) {
  int i = blockIdx.x * 256 + threadIdx.x;
  if (i < n) offs[i] += bsums[blockIdx.x];
}

__global__ __launch_bounds__(256) void fill_kernel(
    const int* __restrict__ e_out, const int* __restrict__ e_in,
    const int* __restrict__ LE, const int* __restrict__ PE,
    const int* __restrict__ offs, int* __restrict__ cnt2,
    int* __restrict__ msg_row, int nE) {
  int e = blockIdx.x * 256 + threadIdx.x;
  if (e >= nE) return;
  int v = e_in[e];
  int pos = offs[v] + atomicAdd(&cnt2[v], 1);
  msg_row[pos] = 4 * e_out[e] + 2 * LE[e] + PE[e];
}

// ---------------------------------------------------------------- gather-reduce: h = x_val + sum(msgs)
__global__ __launch_bounds__(256) void gather_kernel(
    const float* __restrict__ m, const float* __restrict__ x_val,
    const int* __restrict__ offs, const int* __restrict__ msg_row,
    float* __restrict__ h, int nv) {
  int v = blockIdx.x * 4 + (threadIdx.x >> 6);
  if (v >= nv) return;
  int lane = threadIdx.x & 63;
  int beg = offs[v], end = offs[v + 1];
  float2 acc = *(const float2*)(x_val + (long)v * H + lane * 2);
  int p = beg;
  for (; p + 3 < end; p += 4) {
    int r0 = msg_row[p];
    int r1 = msg_row[p + 1];
    int r2 = msg_row[p + 2];
    int r3 = msg_row[p + 3];
    float2 a = *(const float2*)(m + (long)r0 * H + lane * 2);
    float2 b = *(const float2*)(m + (long)r1 * H + lane * 2);
    float2 c = *(const float2*)(m + (long)r2 * H + lane * 2);
    float2 d = *(const float2*)(m + (long)r3 * H + lane * 2);
    acc.x += (a.x + b.x) + (c.x + d.x);
    acc.y += (a.y + b.y) + (c.y + d.y);
  }
  for (; p < end; ++p) {
    int r0 = msg_row[p];
    float2 a = *(const float2*)(m + (long)r0 * H + lane * 2);
    acc.x += a.x;
    acc.y += a.y;
  }
  *(float2*)(h + (long)v * H + lane * 2) = acc;
}

// ---------------------------------------------------------------- fallback atomic scatter
__global__ __launch_bounds__(256) void scatter_kernel(
    const float* __restrict__ m, const int* __restrict__ e_out,
    const int* __restrict__ e_in, const int* __restrict__ LE,
    const int* __restrict__ PE, float* h, int nE) {
  int t = blockIdx.x * 256 + threadIdx.x;
  int edge = t >> 5;
  if (edge >= nE) return;
  int lane = t & 31;
  int c0 = e_out[edge];
  int c1 = e_in[edge];
  int oi = 4 * c0 + 2 * LE[edge] + PE[edge];
  float4 v = *(const float4*)(m + (long)oi * H + lane * 4);
  float* dst = h + (long)c1 * H + lane * 4;
  unsafeAtomicAdd(dst + 0, v.x);
  unsafeAtomicAdd(dst + 1, v.y);
  unsafeAtomicAdd(dst + 2, v.z);
  unsafeAtomicAdd(dst + 3, v.w);
}

extern "C" void kernel_launch(void* const* d_in, const int* in_sizes, int n_in,
                              void* d_out, int out_size, void* d_ws, size_t ws_size,
                              hipStream_t stream) {
  const float* x_val = (const float*)d_in[0];
  const float* r_cst = (const float*)d_in[1];
  const int* edges  = (const int*)d_in[2];   // [2, E]
  const int* LE     = (const int*)d_in[3];
  const int* PE     = (const int*)d_in[4];
  const float* W1  = (const float*)d_in[7];
  const float* b1  = (const float*)d_in[8];
  const float* W2  = (const float*)d_in[9];
  const float* g1  = (const float*)d_in[10];
  const float* bt1 = (const float*)d_in[11];
  const float* W3  = (const float*)d_in[12];
  const float* b3  = (const float*)d_in[13];
  const float* W4  = (const float*)d_in[14];
  const float* g2  = (const float*)d_in[15];
  const float* bt2 = (const float*)d_in[16];

  const int NV = in_sizes[0] / H;
  const int NC = in_sizes[1] / H;
  const int nE = in_sizes[3];

  float* out  = (float*)d_out;
  float* mbuf = (float*)d_ws;                         // 4*NC*H floats

  const size_t mbytes = (size_t)4 * NC * H * sizeof(float);
  int* offs  = (int*)((char*)d_ws + mbytes);          // NV+1
  int* cnt   = offs + (NV + 1);                       // NV
  int* cnt2  = cnt + NV;                              // NV
  int* bsums = cnt2 + NV;                             // up to 1024
  int* msg_row = bsums + 1024;                        // nE
  const size_t csr_bytes = ((size_t)(NV + 1) + NV + NV + 1024 + nE) * sizeof(int);
  const size_t need_csr = mbytes + csr_bytes;

  // weight packs (hi/lo bf16 fragments) after CSR arrays, 64B aligned
  const size_t pack_off = (need_csr + 63) & ~(size_t)63;
  __bf16* W1h = (__bf16*)((char*)d_ws + pack_off);  // 16384 each for W1/W3/W4, 65536 for W2
  __bf16* W1l = W1h + 16384;
  __bf16* W2h = W1l + 16384;
  __bf16* W2l = W2h + 65536;
  __bf16* W3h = W2l + 65536;
  __bf16* W3l = W3h + 16384;
  __bf16* W4h = W3l + 16384;
  __bf16* W4l = W4h + 16384;
  const size_t need_mfma = pack_off + (size_t)(2 * (16384 * 3 + 65536)) * sizeof(__bf16);

  const int nb = (NV + 255) / 256;
  const bool csr_ok = (ws_size >= need_csr) && (nb <= 1024);
  const bool mfma_ok = csr_ok && (ws_size >= need_mfma);

  if (mfma_ok) {
    pack_kernel<<<8, 256, 0, stream>>>(W1, H, H, W1h, W1l);
    pack_kernel<<<32, 256, 0, stream>>>(W2, H, H4, W2h, W2l);
    pack_kernel<<<8, 256, 0, stream>>>(W3, H, H, W3h, W3l);
    pack_kernel<<<8, 256, 0, stream>>>(W4, H, H, W4h, W4l);
    cst_mlp_mfma<<<NC / BM, 256, 0, stream>>>(r_cst, W1h, W1l, b1, W2h, W2l, g1, bt1, mbuf);
  } else {
    cst_mlp_kernel<<<NC / BM, 256, 0, stream>>>(r_cst, W1, b1, W2, g1, bt1, mbuf);
  }

  if (csr_ok) {
    hipMemsetAsync(cnt, 0, (size_t)NV * sizeof(int), stream);
    hipMemsetAsync(cnt2, 0, (size_t)NV * sizeof(int), stream);
    count_kernel<<<(nE + 255) / 256, 256, 0, stream>>>(edges + nE, cnt, nE);
    scan1_kernel<<<nb, 256, 0, stream>>>(cnt, offs, bsums, NV);
    scan2_kernel<<<1, 1024, 0, stream>>>(bsums, nb, offs, NV, nE);
    scan3_kernel<<<nb, 256, 0, stream>>>(offs, bsums, NV);
    fill_kernel<<<(nE + 255) / 256, 256, 0, stream>>>(edges, edges + nE, LE, PE, offs, cnt2,
                                                      msg_row, nE);
    gather_kernel<<<(NV + 3) / 4, 256, 0, stream>>>(mbuf, x_val, offs, msg_row, out, NV);
  } else {
    copy_kernel<<<2048, 256, 0, stream>>>((const float4*)x_val, (float4*)out, NV * H / 4);
    scatter_kernel<<<(nE * 32 + 255) / 256, 256, 0, stream>>>(mbuf, edges, edges + nE, LE, PE,
                                                              out, nE);
  }

  if (mfma_ok) {
    val_mlp_mfma<<<NV / BM, 256, 0, stream>>>(out, x_val, W3h, W3l, b3, W4h, W4l, g2, bt2, out);
  } else {
    val_mlp_kernel<<<NV / BM, 256, 0, stream>>>(out, x_val, W3, b3, W4, g2, bt2, out);
  }
}

// Round 7
// 653.652 us; speedup vs baseline: 5.0088x; 1.0071x over previous
//
#include <hip/hip_runtime.h>
#include <hip/hip_bf16.h>

#define H 128
#define H4 512
#define BM 16   // fallback fp32 kernels
#define BM2 32  // MFMA kernels

typedef __bf16 bf16x8 __attribute__((ext_vector_type(8)));
typedef float f32x4 __attribute__((ext_vector_type(4)));

__device__ inline f32x4 mfma16(bf16x8 a, bf16x8 b, f32x4 c) {
  return __builtin_amdgcn_mfma_f32_16x16x32_bf16(a, b, c, 0, 0, 0);
}

// ---------------------------------------------------------------- weight pack: fp32 [K][N] -> hi/lo bf16 MFMA B-fragments
// frag layout: tile = nt*(K/32)+kt ; lane l holds B[kt*32+(l>>4)*8 + i][nt*16+(l&15)], i=0..7
__global__ __launch_bounds__(256) void pack_kernel(const float* __restrict__ W, int K, int N,
                                                   __bf16* __restrict__ hi,
                                                   __bf16* __restrict__ lo) {
  int idx = blockIdx.x * 256 + threadIdx.x;
  int total = (N >> 4) * (K >> 5) * 64;
  if (idx >= total) return;
  int lane = idx & 63;
  int tile = idx >> 6;
  int KT = K >> 5;
  int nt = tile / KT, kt = tile - nt * KT;
  int col = nt * 16 + (lane & 15);
  int k0 = kt * 32 + (lane >> 4) * 8;
#pragma unroll
  for (int i = 0; i < 8; ++i) {
    float x = W[(long)(k0 + i) * N + col];
    __bf16 h = (__bf16)x;
    hi[(long)idx * 8 + i] = h;
    lo[(long)idx * 8 + i] = (__bf16)(x - (float)h);
  }
}

// ---------------------------------------------------------------- copy (fallback path only)
__global__ __launch_bounds__(256) void copy_kernel(const float4* __restrict__ src,
                                                   float4* __restrict__ dst, int n4) {
  int i = blockIdx.x * 256 + threadIdx.x;
  int stride = gridDim.x * 256;
  for (; i < n4; i += stride) dst[i] = src[i];
}

// ---------------------------------------------------------------- helpers
__device__ inline void split8(const float* p, bf16x8& hi, bf16x8& lo) {
  float4 u = *(const float4*)p, v = *(const float4*)(p + 4);
  float vals[8] = {u.x, u.y, u.z, u.w, v.x, v.y, v.z, v.w};
#pragma unroll
  for (int i = 0; i < 8; ++i) {
    __bf16 hh = (__bf16)vals[i];
    hi[i] = hh;
    lo[i] = (__bf16)(vals[i] - (float)hh);
  }
}

// ---------------------------------------------------------------- cst_send MLP + LN(512), MFMA split-bf16, 32 rows/block
// D kept in registers; LN via register partials + 1KB LDS reduce (no Ds buffer).
__global__ __launch_bounds__(256) void cst_mlp_mfma(
    const float* __restrict__ r_cst,
    const __bf16* __restrict__ W1h, const __bf16* __restrict__ W1l,
    const float* __restrict__ b1,
    const __bf16* __restrict__ W2h, const __bf16* __restrict__ W2l,
    const float* __restrict__ g1, const float* __restrict__ bt1,
    float* __restrict__ m) {
  __shared__ float As[BM2][132];      // 16.9 KB (+4 pad)
  __shared__ float Cs[BM2][132];      // 16.9 KB
  __shared__ float part_s[BM2][4];    // per-row per-wave partial sums
  __shared__ float part_q[BM2][4];
  __shared__ float mu_s[BM2], rs_s[BM2];

  const int tid = threadIdx.x;
  const int wave = tid >> 6, lane = tid & 63;
  const long row0 = (long)blockIdx.x * BM2;

  // stage A (32x128), coalesced
  {
    const float4* src = (const float4*)(r_cst + row0 * H);
#pragma unroll
    for (int i = 0; i < 4; ++i) {
      int idx = tid + i * 256;  // 0..1023 float4s
      int r = idx >> 5, c4 = idx & 31;
      *(float4*)&As[r][c4 * 4] = src[idx];
    }
  }
  __syncthreads();

  const int fr = lane & 15;
  const int fk = (lane >> 4) * 8;
  const int rowb = (lane >> 4) * 4;

  // A fragments [mt][kt]
  bf16x8 a_hi[2][4], a_lo[2][4];
#pragma unroll
  for (int mt = 0; mt < 2; ++mt)
#pragma unroll
    for (int kt = 0; kt < 4; ++kt) split8(&As[mt * 16 + fr][kt * 32 + fk], a_hi[mt][kt], a_lo[mt][kt]);

  // GEMM1: C = relu(A@W1+b1); wave -> n-tiles {2w,2w+1}; B loaded once per kt, used by both mt
#pragma unroll
  for (int t = 0; t < 2; ++t) {
    const int nt = wave * 2 + t;
    f32x4 acc0 = {0.f, 0.f, 0.f, 0.f}, acc1 = {0.f, 0.f, 0.f, 0.f};
#pragma unroll
    for (int kt = 0; kt < 4; ++kt) {
      const long fi = (long)((nt * 4 + kt) * 64 + lane) * 8;
      bf16x8 bh = *(const bf16x8*)(W1h + fi);
      bf16x8 bl = *(const bf16x8*)(W1l + fi);
      acc0 = mfma16(a_hi[0][kt], bh, acc0);
      acc0 = mfma16(a_lo[0][kt], bh, acc0);
      acc0 = mfma16(a_hi[0][kt], bl, acc0);
      acc1 = mfma16(a_hi[1][kt], bh, acc1);
      acc1 = mfma16(a_lo[1][kt], bh, acc1);
      acc1 = mfma16(a_hi[1][kt], bl, acc1);
    }
    const int col = nt * 16 + fr;
    const float bb = b1[col];
#pragma unroll
    for (int r = 0; r < 4; ++r) {
      Cs[rowb + r][col] = fmaxf(acc0[r] + bb, 0.f);
      Cs[16 + rowb + r][col] = fmaxf(acc1[r] + bb, 0.f);
    }
  }
  __syncthreads();

  // C fragments (A frags dead; compiler reuses regs)
  bf16x8 c_hi[2][4], c_lo[2][4];
#pragma unroll
  for (int mt = 0; mt < 2; ++mt)
#pragma unroll
    for (int kt = 0; kt < 4; ++kt) split8(&Cs[mt * 16 + fr][kt * 32 + fk], c_hi[mt][kt], c_lo[mt][kt]);

  // GEMM2: D = C@W2 (in registers) + per-lane LN partials; wave -> n-tiles {8w..8w+7}
  f32x4 d[2][8];
  float ss[2][4], qq[2][4];
#pragma unroll
  for (int mt = 0; mt < 2; ++mt)
#pragma unroll
    for (int r = 0; r < 4; ++r) ss[mt][r] = qq[mt][r] = 0.f;

#pragma unroll
  for (int t = 0; t < 8; ++t) {
    const int nt = wave * 8 + t;
    f32x4 acc0 = {0.f, 0.f, 0.f, 0.f}, acc1 = {0.f, 0.f, 0.f, 0.f};
#pragma unroll
    for (int kt = 0; kt < 4; ++kt) {
      const long fi = (long)((nt * 4 + kt) * 64 + lane) * 8;
      bf16x8 bh = *(const bf16x8*)(W2h + fi);
      bf16x8 bl = *(const bf16x8*)(W2l + fi);
      acc0 = mfma16(c_hi[0][kt], bh, acc0);
      acc0 = mfma16(c_lo[0][kt], bh, acc0);
      acc0 = mfma16(c_hi[0][kt], bl, acc0);
      acc1 = mfma16(c_hi[1][kt], bh, acc1);
      acc1 = mfma16(c_lo[1][kt], bh, acc1);
      acc1 = mfma16(c_hi[1][kt], bl, acc1);
    }
    d[0][t] = acc0;
    d[1][t] = acc1;
#pragma unroll
    for (int r = 0; r < 4; ++r) {
      ss[0][r] += acc0[r];
      qq[0][r] += acc0[r] * acc0[r];
      ss[1][r] += acc1[r];
      qq[1][r] += acc1[r] * acc1[r];
    }
  }

  // reduce partials over the 16-lane fr-group (xor 1,2,4,8 stays in-group)
#pragma unroll
  for (int mt = 0; mt < 2; ++mt)
#pragma unroll
    for (int r = 0; r < 4; ++r) {
      float s = ss[mt][r], q = qq[mt][r];
#pragma unroll
      for (int off = 1; off < 16; off <<= 1) {
        s += __shfl_xor(s, off);
        q += __shfl_xor(q, off);
      }
      if (fr == 0) {
        part_s[mt * 16 + rowb + r][wave] = s;
        part_q[mt * 16 + rowb + r][wave] = q;
      }
    }
  __syncthreads();

  if (tid < BM2) {
    float s = part_s[tid][0] + part_s[tid][1] + part_s[tid][2] + part_s[tid][3];
    float q = part_q[tid][0] + part_q[tid][1] + part_q[tid][2] + part_q[tid][3];
    float mu = s * (1.f / H4);
    mu_s[tid] = mu;
    rs_s[tid] = rsqrtf(q * (1.f / H4) - mu * mu + 1e-5f);
  }
  __syncthreads();

  // normalize in registers, store direct (16-lane x 4B = 64B contiguous segments)
#pragma unroll
  for (int t = 0; t < 8; ++t) {
    const int col = (wave * 8 + t) * 16 + fr;
    const float g = g1[col], b = bt1[col];
#pragma unroll
    for (int mt = 0; mt < 2; ++mt) {
#pragma unroll
      for (int r = 0; r < 4; ++r) {
        const int row = mt * 16 + rowb + r;
        m[(row0 + row) * H4 + col] = (d[mt][t][r] - mu_s[row]) * rs_s[row] * g + b;
      }
    }
  }
}

// ---------------------------------------------------------------- val_rec MLP + LN(128) + residual, MFMA split-bf16, 32 rows/block
__global__ __launch_bounds__(256) void val_mlp_mfma(
    const float* h, const float* __restrict__ x_val,
    const __bf16* __restrict__ W3h, const __bf16* __restrict__ W3l,
    const float* __restrict__ b3,
    const __bf16* __restrict__ W4h, const __bf16* __restrict__ W4l,
    const float* __restrict__ g2, const float* __restrict__ bt2,
    float* out) {
  __shared__ float As[BM2][132];
  __shared__ float Cs[BM2][132];
  __shared__ float part_s[BM2][4];
  __shared__ float part_q[BM2][4];
  __shared__ float mu_s[BM2], rs_s[BM2];

  const int tid = threadIdx.x;
  const int wave = tid >> 6, lane = tid & 63;
  const long row0 = (long)blockIdx.x * BM2;

  {
    const float4* src = (const float4*)(h + row0 * H);
#pragma unroll
    for (int i = 0; i < 4; ++i) {
      int idx = tid + i * 256;
      int r = idx >> 5, c4 = idx & 31;
      *(float4*)&As[r][c4 * 4] = src[idx];
    }
  }
  __syncthreads();

  const int fr = lane & 15;
  const int fk = (lane >> 4) * 8;
  const int rowb = (lane >> 4) * 4;

  bf16x8 a_hi[2][4], a_lo[2][4];
#pragma unroll
  for (int mt = 0; mt < 2; ++mt)
#pragma unroll
    for (int kt = 0; kt < 4; ++kt) split8(&As[mt * 16 + fr][kt * 32 + fk], a_hi[mt][kt], a_lo[mt][kt]);

  // GEMM1: wave -> n-tiles {2w,2w+1}
#pragma unroll
  for (int t = 0; t < 2; ++t) {
    const int nt = wave * 2 + t;
    f32x4 acc0 = {0.f, 0.f, 0.f, 0.f}, acc1 = {0.f, 0.f, 0.f, 0.f};
#pragma unroll
    for (int kt = 0; kt < 4; ++kt) {
      const long fi = (long)((nt * 4 + kt) * 64 + lane) * 8;
      bf16x8 bh = *(const bf16x8*)(W3h + fi);
      bf16x8 bl = *(const bf16x8*)(W3l + fi);
      acc0 = mfma16(a_hi[0][kt], bh, acc0);
      acc0 = mfma16(a_lo[0][kt], bh, acc0);
      acc0 = mfma16(a_hi[0][kt], bl, acc0);
      acc1 = mfma16(a_hi[1][kt], bh, acc1);
      acc1 = mfma16(a_lo[1][kt], bh, acc1);
      acc1 = mfma16(a_hi[1][kt], bl, acc1);
    }
    const int col = nt * 16 + fr;
    const float bb = b3[col];
#pragma unroll
    for (int r = 0; r < 4; ++r) {
      Cs[rowb + r][col] = fmaxf(acc0[r] + bb, 0.f);
      Cs[16 + rowb + r][col] = fmaxf(acc1[r] + bb, 0.f);
    }
  }
  __syncthreads();

  bf16x8 c_hi[2][4], c_lo[2][4];
#pragma unroll
  for (int mt = 0; mt < 2; ++mt)
#pragma unroll
    for (int kt = 0; kt < 4; ++kt) split8(&Cs[mt * 16 + fr][kt * 32 + fk], c_hi[mt][kt], c_lo[mt][kt]);

  // GEMM2: wave -> n-tiles {2w,2w+1}; D in registers
  f32x4 d[2][2];
  float ss[2][4], qq[2][4];
#pragma unroll
  for (int mt = 0; mt < 2; ++mt)
#pragma unroll
    for (int r = 0; r < 4; ++r) ss[mt][r] = qq[mt][r] = 0.f;

#pragma unroll
  for (int t = 0; t < 2; ++t) {
    const int nt = wave * 2 + t;
    f32x4 acc0 = {0.f, 0.f, 0.f, 0.f}, acc1 = {0.f, 0.f, 0.f, 0.f};
#pragma unroll
    for (int kt = 0; kt < 4; ++kt) {
      const long fi = (long)((nt * 4 + kt) * 64 + lane) * 8;
      bf16x8 bh = *(const bf16x8*)(W4h + fi);
      bf16x8 bl = *(const bf16x8*)(W4l + fi);
      acc0 = mfma16(c_hi[0][kt], bh, acc0);
      acc0 = mfma16(c_lo[0][kt], bh, acc0);
      acc0 = mfma16(c_hi[0][kt], bl, acc0);
      acc1 = mfma16(c_hi[1][kt], bh, acc1);
      acc1 = mfma16(c_lo[1][kt], bh, acc1);
      acc1 = mfma16(c_hi[1][kt], bl, acc1);
    }
    d[0][t] = acc0;
    d[1][t] = acc1;
#pragma unroll
    for (int r = 0; r < 4; ++r) {
      ss[0][r] += acc0[r];
      qq[0][r] += acc0[r] * acc0[r];
      ss[1][r] += acc1[r];
      qq[1][r] += acc1[r] * acc1[r];
    }
  }

#pragma unroll
  for (int mt = 0; mt < 2; ++mt)
#pragma unroll
    for (int r = 0; r < 4; ++r) {
      float s = ss[mt][r], q = qq[mt][r];
#pragma unroll
      for (int off = 1; off < 16; off <<= 1) {
        s += __shfl_xor(s, off);
        q += __shfl_xor(q, off);
      }
      if (fr == 0) {
        part_s[mt * 16 + rowb + r][wave] = s;
        part_q[mt * 16 + rowb + r][wave] = q;
      }
    }
  __syncthreads();

  if (tid < BM2) {
    float s = part_s[tid][0] + part_s[tid][1] + part_s[tid][2] + part_s[tid][3];
    float q = part_q[tid][0] + part_q[tid][1] + part_q[tid][2] + part_q[tid][3];
    float mu = s * (1.f / H);
    mu_s[tid] = mu;
    rs_s[tid] = rsqrtf(q * (1.f / H) - mu * mu + 1e-5f);
  }
  __syncthreads();

  // normalize + affine + residual, direct store
#pragma unroll
  for (int t = 0; t < 2; ++t) {
    const int col = (wave * 2 + t) * 16 + fr;
    const float g = g2[col], b = bt2[col];
#pragma unroll
    for (int mt = 0; mt < 2; ++mt) {
#pragma unroll
      for (int r = 0; r < 4; ++r) {
        const int row = mt * 16 + rowb + r;
        const float xv = x_val[(row0 + row) * H + col];
        out[(row0 + row) * H + col] = (d[mt][t][r] - mu_s[row]) * rs_s[row] * g + b + xv;
      }
    }
  }
}

// ---------------------------------------------------------------- fp32 fallback MLPs
__global__ __launch_bounds__(256) void cst_mlp_kernel(
    const float* __restrict__ r_cst,
    const float* __restrict__ W1, const float* __restrict__ b1,
    const float* __restrict__ W2, const float* __restrict__ g1,
    const float* __restrict__ bt1, float* __restrict__ m) {
  __shared__ float As[BM][H];
  __shared__ float Cs[BM][H];
  __shared__ float Ds[BM][H4];
  __shared__ float mu_s[BM], rs_s[BM];
  const int tid = threadIdx.x;
  const long row0 = (long)blockIdx.x * BM;
  {
    const float4* src = (const float4*)(r_cst + row0 * H);
    float4* dst = (float4*)&As[0][0];
#pragma unroll
    for (int i = 0; i < 2; ++i) dst[tid + i * 256] = src[tid + i * 256];
  }
  __syncthreads();
  {
    const int j = tid & (H - 1);
    const int r0 = (tid >> 7) * 8;
    float acc[8] = {0, 0, 0, 0, 0, 0, 0, 0};
#pragma unroll 4
    for (int k = 0; k < H; ++k) {
      float w = W1[k * H + j];
#pragma unroll
      for (int r = 0; r < 8; ++r) acc[r] = fmaf(As[r0 + r][k], w, acc[r]);
    }
    float bb = b1[j];
#pragma unroll
    for (int r = 0; r < 8; ++r) Cs[r0 + r][j] = fmaxf(acc[r] + bb, 0.f);
  }
  __syncthreads();
  {
    const int j = tid * 2;
    float acc[BM][2];
#pragma unroll
    for (int r = 0; r < BM; ++r) acc[r][0] = acc[r][1] = 0.f;
    for (int k = 0; k < H; k += 4) {
      float4 c[BM];
#pragma unroll
      for (int r = 0; r < BM; ++r) c[r] = *(const float4*)&Cs[r][k];
#pragma unroll
      for (int kk = 0; kk < 4; ++kk) {
        const float2 w = *(const float2*)&W2[(k + kk) * H4 + j];
#pragma unroll
        for (int r = 0; r < BM; ++r) {
          float cv = (&c[r].x)[kk];
          acc[r][0] = fmaf(cv, w.x, acc[r][0]);
          acc[r][1] = fmaf(cv, w.y, acc[r][1]);
        }
      }
    }
#pragma unroll
    for (int r = 0; r < BM; ++r) {
      Ds[r][j] = acc[r][0];
      Ds[r][j + 1] = acc[r][1];
    }
  }
  __syncthreads();
  {
    const int wv = tid >> 6, lane = tid & 63;
    for (int r = wv * 4; r < wv * 4 + 4; ++r) {
      float s = 0.f, q = 0.f;
      const float4* rowp = (const float4*)&Ds[r][0];
#pragma unroll
      for (int i = 0; i < 2; ++i) {
        float4 v = rowp[lane * 2 + i];
        s += v.x + v.y + v.z + v.w;
        q += v.x * v.x + v.y * v.y + v.z * v.z + v.w * v.w;
      }
#pragma unroll
      for (int off = 32; off; off >>= 1) {
        s += __shfl_xor(s, off);
        q += __shfl_xor(q, off);
      }
      if (lane == 0) {
        float mu = s * (1.f / H4);
        mu_s[r] = mu;
        rs_s[r] = rsqrtf(q * (1.f / H4) - mu * mu + 1e-5f);
      }
    }
  }
  __syncthreads();
  {
    float4* out4 = (float4*)(m + row0 * H4);
    const float4* D4 = (const float4*)&Ds[0][0];
    const float4* g4 = (const float4*)g1;
    const float4* b4 = (const float4*)bt1;
#pragma unroll
    for (int it = 0; it < 8; ++it) {
      int e4 = tid + it * 256;
      int r = e4 >> 7;
      int c4 = e4 & 127;
      float4 v = D4[e4];
      float4 g = g4[c4], b = b4[c4];
      float mu = mu_s[r], rs = rs_s[r];
      float4 o;
      o.x = (v.x - mu) * rs * g.x + b.x;
      o.y = (v.y - mu) * rs * g.y + b.y;
      o.z = (v.z - mu) * rs * g.z + b.z;
      o.w = (v.w - mu) * rs * g.w + b.w;
      out4[e4] = o;
    }
  }
}

__global__ __launch_bounds__(256) void val_mlp_kernel(
    const float* h, const float* __restrict__ x_val,
    const float* __restrict__ W3, const float* __restrict__ b3,
    const float* __restrict__ W4, const float* __restrict__ g2,
    const float* __restrict__ bt2, float* out) {
  __shared__ float As[BM][H];
  __shared__ float Cs[BM][H];
  __shared__ float Ds[BM][H];
  __shared__ float mu_s[BM], rs_s[BM];
  const int tid = threadIdx.x;
  const long row0 = (long)blockIdx.x * BM;
  {
    const float4* src = (const float4*)(h + row0 * H);
    float4* dst = (float4*)&As[0][0];
#pragma unroll
    for (int i = 0; i < 2; ++i) dst[tid + i * 256] = src[tid + i * 256];
  }
  __syncthreads();
  const int j = tid & (H - 1);
  const int r0 = (tid >> 7) * 8;
  {
    float acc[8] = {0, 0, 0, 0, 0, 0, 0, 0};
#pragma unroll 4
    for (int k = 0; k < H; ++k) {
      float w = W3[k * H + j];
#pragma unroll
      for (int r = 0; r < 8; ++r) acc[r] = fmaf(As[r0 + r][k], w, acc[r]);
    }
    float bb = b3[j];
#pragma unroll
    for (int r = 0; r < 8; ++r) Cs[r0 + r][j] = fmaxf(acc[r] + bb, 0.f);
  }
  __syncthreads();
  {
    float acc[8] = {0, 0, 0, 0, 0, 0, 0, 0};
#pragma unroll 4
    for (int k = 0; k < H; ++k) {
      float w = W4[k * H + j];
#pragma unroll
      for (int r = 0; r < 8; ++r) acc[r] = fmaf(Cs[r0 + r][k], w, acc[r]);
    }
#pragma unroll
    for (int r = 0; r < 8; ++r) Ds[r0 + r][j] = acc[r];
  }
  __syncthreads();
  {
    const int wv = tid >> 6, lane = tid & 63;
    for (int r = wv * 4; r < wv * 4 + 4; ++r) {
      float2 v = *(const float2*)&Ds[r][lane * 2];
      float s = v.x + v.y, q = v.x * v.x + v.y * v.y;
#pragma unroll
      for (int off = 32; off; off >>= 1) {
        s += __shfl_xor(s, off);
        q += __shfl_xor(q, off);
      }
      if (lane == 0) {
        float mu = s * (1.f / H);
        mu_s[r] = mu;
        rs_s[r] = rsqrtf(q * (1.f / H) - mu * mu + 1e-5f);
      }
    }
  }
  __syncthreads();
  {
    float4* out4 = (float4*)(out + row0 * H);
    const float4* x4 = (const float4*)(x_val + row0 * H);
    const float4* D4 = (const float4*)&Ds[0][0];
    const float4* g4 = (const float4*)g2;
    const float4* b4 = (const float4*)bt2;
#pragma unroll
    for (int it = 0; it < 2; ++it) {
      int e4 = tid + it * 256;
      int r = e4 >> 5;
      int c4 = e4 & 31;
      float4 v = D4[e4];
      float4 g = g4[c4], b = b4[c4], xv = x4[e4];
      float mu = mu_s[r], rs = rs_s[r];
      float4 o;
      o.x = (v.x - mu) * rs * g.x + b.x + xv.x;
      o.y = (v.y - mu) * rs * g.y + b.y + xv.y;
      o.z = (v.z - mu) * rs * g.z + b.z + xv.z;
      o.w = (v.w - mu) * rs * g.w + b.w + xv.w;
      out4[e4] = o;
    }
  }
}

// ---------------------------------------------------------------- CSR build
__global__ __launch_bounds__(256) void count_kernel(const int* __restrict__ e_in,
                                                    int* __restrict__ cnt, int nE) {
  int i = blockIdx.x * 256 + threadIdx.x;
  if (i < nE) atomicAdd(&cnt[e_in[i]], 1);
}

__device__ inline int wave_incl_scan(int x) {
#pragma unroll
  for (int off = 1; off < 64; off <<= 1) {
    int y = __shfl_up(x, off);
    if ((threadIdx.x & 63) >= off) x += y;
  }
  return x;
}

__global__ __launch_bounds__(256) void scan1_kernel(const int* __restrict__ cnt,
                                                    int* __restrict__ offs,
                                                    int* __restrict__ bsums, int n) {
  int i = blockIdx.x * 256 + threadIdx.x;
  int v = (i < n) ? cnt[i] : 0;
  int incl = wave_incl_scan(v);
  __shared__ int wsum[4];
  int wv = threadIdx.x >> 6, lane = threadIdx.x & 63;
  if (lane == 63) wsum[wv] = incl;
  __syncthreads();
  int add = 0;
  for (int w = 0; w < wv; ++w) add += wsum[w];
  if (i < n) offs[i] = incl - v + add;
  if (threadIdx.x == 255) bsums[blockIdx.x] = incl + add;
}

__global__ __launch_bounds__(1024) void scan2_kernel(int* __restrict__ bsums, int nb,
                                                     int* __restrict__ offs, int n, int total) {
  __shared__ int s[1024];
  int t = threadIdx.x;
  int orig = (t < nb) ? bsums[t] : 0;
  s[t] = orig;
  __syncthreads();
  for (int off = 1; off < 1024; off <<= 1) {
    int v = (t >= off) ? s[t - off] : 0;
    __syncthreads();
    s[t] += v;
    __syncthreads();
  }
  if (t < nb) bsums[t] = s[t] - orig;
  if (t == 0) offs[n] = total;
}

__global__ __launch_bounds__(256) void scan3_kernel(int* __restrict__ offs,
                                                    const int* __restrict__ bsums, int n) {
  int i = blockIdx.x * 256 + threadIdx.x;
  if (i < n) offs[i] += bsums[blockIdx.x];
}

__global__ __launch_bounds__(256) void fill_kernel(
    const int* __restrict__ e_out, const int* __restrict__ e_in,
    const int* __restrict__ LE, const int* __restrict__ PE,
    const int* __restrict__ offs, int* __restrict__ cnt2,
    int* __restrict__ msg_row, int nE) {
  int e = blockIdx.x * 256 + threadIdx.x;
  if (e >= nE) return;
  int v = e_in[e];
  int pos = offs[v] + atomicAdd(&cnt2[v], 1);
  msg_row[pos] = 4 * e_out[e] + 2 * LE[e] + PE[e];
}

// ---------------------------------------------------------------- gather-reduce: h = x_val + sum(msgs)
__global__ __launch_bounds__(256) void gather_kernel(
    const float* __restrict__ m, const float* __restrict__ x_val,
    const int* __restrict__ offs, const int* __restrict__ msg_row,
    float* __restrict__ h, int nv) {
  int v = blockIdx.x * 4 + (threadIdx.x >> 6);
  if (v >= nv) return;
  int lane = threadIdx.x & 63;
  int beg = offs[v], end = offs[v + 1];
  float2 acc = *(const float2*)(x_val + (long)v * H + lane * 2);
  int p = beg;
  for (; p + 3 < end; p += 4) {
    int r0 = msg_row[p];
    int r1 = msg_row[p + 1];
    int r2 = msg_row[p + 2];
    int r3 = msg_row[p + 3];
    float2 a = *(const float2*)(m + (long)r0 * H + lane * 2);
    float2 b = *(const float2*)(m + (long)r1 * H + lane * 2);
    float2 c = *(const float2*)(m + (long)r2 * H + lane * 2);
    float2 d = *(const float2*)(m + (long)r3 * H + lane * 2);
    acc.x += (a.x + b.x) + (c.x + d.x);
    acc.y += (a.y + b.y) + (c.y + d.y);
  }
  for (; p < end; ++p) {
    int r0 = msg_row[p];
    float2 a = *(const float2*)(m + (long)r0 * H + lane * 2);
    acc.x += a.x;
    acc.y += a.y;
  }
  *(float2*)(h + (long)v * H + lane * 2) = acc;
}

// ---------------------------------------------------------------- fallback atomic scatter
__global__ __launch_bounds__(256) void scatter_kernel(
    const float* __restrict__ m, const int* __restrict__ e_out,
    const int* __restrict__ e_in, const int* __restrict__ LE,
    const int* __restrict__ PE, float* h, int nE) {
  int t = blockIdx.x * 256 + threadIdx.x;
  int edge = t >> 5;
  if (edge >= nE) return;
  int lane = t & 31;
  int c0 = e_out[edge];
  int c1 = e_in[edge];
  int oi = 4 * c0 + 2 * LE[edge] + PE[edge];
  float4 v = *(const float4*)(m + (long)oi * H + lane * 4);
  float* dst = h + (long)c1 * H + lane * 4;
  unsafeAtomicAdd(dst + 0, v.x);
  unsafeAtomicAdd(dst + 1, v.y);
  unsafeAtomicAdd(dst + 2, v.z);
  unsafeAtomicAdd(dst + 3, v.w);
}

extern "C" void kernel_launch(void* const* d_in, const int* in_sizes, int n_in,
                              void* d_out, int out_size, void* d_ws, size_t ws_size,
                              hipStream_t stream) {
  const float* x_val = (const float*)d_in[0];
  const float* r_cst = (const float*)d_in[1];
  const int* edges  = (const int*)d_in[2];   // [2, E]
  const int* LE     = (const int*)d_in[3];
  const int* PE     = (const int*)d_in[4];
  const float* W1  = (const float*)d_in[7];
  const float* b1  = (const float*)d_in[8];
  const float* W2  = (const float*)d_in[9];
  const float* g1  = (const float*)d_in[10];
  const float* bt1 = (const float*)d_in[11];
  const float* W3  = (const float*)d_in[12];
  const float* b3  = (const float*)d_in[13];
  const float* W4  = (const float*)d_in[14];
  const float* g2  = (const float*)d_in[15];
  const float* bt2 = (const float*)d_in[16];

  const int NV = in_sizes[0] / H;
  const int NC = in_sizes[1] / H;
  const int nE = in_sizes[3];

  float* out  = (float*)d_out;
  float* mbuf = (float*)d_ws;                         // 4*NC*H floats

  const size_t mbytes = (size_t)4 * NC * H * sizeof(float);
  int* offs  = (int*)((char*)d_ws + mbytes);          // NV+1
  int* cnt   = offs + (NV + 1);                       // NV
  int* cnt2  = cnt + NV;                              // NV
  int* bsums = cnt2 + NV;                             // up to 1024
  int* msg_row = bsums + 1024;                        // nE
  const size_t csr_bytes = ((size_t)(NV + 1) + NV + NV + 1024 + nE) * sizeof(int);
  const size_t need_csr = mbytes + csr_bytes;

  // weight packs (hi/lo bf16 fragments) after CSR arrays, 64B aligned
  const size_t pack_off = (need_csr + 63) & ~(size_t)63;
  __bf16* W1h = (__bf16*)((char*)d_ws + pack_off);
  __bf16* W1l = W1h + 16384;
  __bf16* W2h = W1l + 16384;
  __bf16* W2l = W2h + 65536;
  __bf16* W3h = W2l + 65536;
  __bf16* W3l = W3h + 16384;
  __bf16* W4h = W3l + 16384;
  __bf16* W4l = W4h + 16384;
  const size_t need_mfma = pack_off + (size_t)(2 * (16384 * 3 + 65536)) * sizeof(__bf16);

  const int nb = (NV + 255) / 256;
  const bool csr_ok = (ws_size >= need_csr) && (nb <= 1024);
  const bool mfma_ok = csr_ok && (ws_size >= need_mfma) && (NC % BM2 == 0) && (NV % BM2 == 0);

  if (mfma_ok) {
    pack_kernel<<<8, 256, 0, stream>>>(W1, H, H, W1h, W1l);
    pack_kernel<<<32, 256, 0, stream>>>(W2, H, H4, W2h, W2l);
    pack_kernel<<<8, 256, 0, stream>>>(W3, H, H, W3h, W3l);
    pack_kernel<<<8, 256, 0, stream>>>(W4, H, H, W4h, W4l);
    cst_mlp_mfma<<<NC / BM2, 256, 0, stream>>>(r_cst, W1h, W1l, b1, W2h, W2l, g1, bt1, mbuf);
  } else {
    cst_mlp_kernel<<<NC / BM, 256, 0, stream>>>(r_cst, W1, b1, W2, g1, bt1, mbuf);
  }

  if (csr_ok) {
    hipMemsetAsync(cnt, 0, (size_t)NV * sizeof(int), stream);
    hipMemsetAsync(cnt2, 0, (size_t)NV * sizeof(int), stream);
    count_kernel<<<(nE + 255) / 256, 256, 0, stream>>>(edges + nE, cnt, nE);
    scan1_kernel<<<nb, 256, 0, stream>>>(cnt, offs, bsums, NV);
    scan2_kernel<<<1, 1024, 0, stream>>>(bsums, nb, offs, NV, nE);
    scan3_kernel<<<nb, 256, 0, stream>>>(offs, bsums, NV);
    fill_kernel<<<(nE + 255) / 256, 256, 0, stream>>>(edges, edges + nE, LE, PE, offs, cnt2,
                                                      msg_row, nE);
    gather_kernel<<<(NV + 3) / 4, 256, 0, stream>>>(mbuf, x_val, offs, msg_row, out, NV);
  } else {
    copy_kernel<<<2048, 256, 0, stream>>>((const float4*)x_val, (float4*)out, NV * H / 4);
    scatter_kernel<<<(nE * 32 + 255) / 256, 256, 0, stream>>>(mbuf, edges, edges + nE, LE, PE,
                                                              out, nE);
  }

  if (mfma_ok) {
    val_mlp_mfma<<<NV / BM2, 256, 0, stream>>>(out, x_val, W3h, W3l, b3, W4h, W4l, g2, bt2, out);
  } else {
    val_mlp_kernel<<<NV / BM, 256, 0, stream>>>(out, x_val, W3, b3, W4, g2, bt2, out);
  }
}

// Round 8
// 635.707 us; speedup vs baseline: 5.1502x; 1.0282x over previous
//
#include <hip/hip_runtime.h>
#include <hip/hip_bf16.h>

#define H 128
#define H4 512
#define BM 16   // fallback fp32 kernels
#define BM2 32  // MFMA kernels
#define CPAD 136  // 128 + 8 bf16 pad -> row stride 272B = 4 banks offset, 2-way (free)

typedef __bf16 bf16x8 __attribute__((ext_vector_type(8)));
typedef float f32x4 __attribute__((ext_vector_type(4)));

__device__ inline f32x4 mfma16(bf16x8 a, bf16x8 b, f32x4 c) {
  return __builtin_amdgcn_mfma_f32_16x16x32_bf16(a, b, c, 0, 0, 0);
}

// ---------------------------------------------------------------- weight pack: fp32 [K][N] -> hi/lo bf16 MFMA B-fragments
// frag layout: tile = nt*(K/32)+kt ; lane l holds B[kt*32+(l>>4)*8 + i][nt*16+(l&15)], i=0..7
__global__ __launch_bounds__(256) void pack_kernel(const float* __restrict__ W, int K, int N,
                                                   __bf16* __restrict__ hi,
                                                   __bf16* __restrict__ lo) {
  int idx = blockIdx.x * 256 + threadIdx.x;
  int total = (N >> 4) * (K >> 5) * 64;
  if (idx >= total) return;
  int lane = idx & 63;
  int tile = idx >> 6;
  int KT = K >> 5;
  int nt = tile / KT, kt = tile - nt * KT;
  int col = nt * 16 + (lane & 15);
  int k0 = kt * 32 + (lane >> 4) * 8;
#pragma unroll
  for (int i = 0; i < 8; ++i) {
    float x = W[(long)(k0 + i) * N + col];
    __bf16 h = (__bf16)x;
    hi[(long)idx * 8 + i] = h;
    lo[(long)idx * 8 + i] = (__bf16)(x - (float)h);
  }
}

// ---------------------------------------------------------------- copy (fallback path only)
__global__ __launch_bounds__(256) void copy_kernel(const float4* __restrict__ src,
                                                   float4* __restrict__ dst, int n4) {
  int i = blockIdx.x * 256 + threadIdx.x;
  int stride = gridDim.x * 256;
  for (; i < n4; i += stride) dst[i] = src[i];
}

// ---------------------------------------------------------------- helpers
__device__ inline void split8(const float* p, bf16x8& hi, bf16x8& lo) {
  float4 u = *(const float4*)p, v = *(const float4*)(p + 4);
  float vals[8] = {u.x, u.y, u.z, u.w, v.x, v.y, v.z, v.w};
#pragma unroll
  for (int i = 0; i < 8; ++i) {
    __bf16 hh = (__bf16)vals[i];
    hi[i] = hh;
    lo[i] = (__bf16)(vals[i] - (float)hh);
  }
}

// ---------------------------------------------------------------- cst_send MLP + LN(512), MFMA split-bf16
// A frags direct from global; C staged in LDS as pre-split bf16 hi/lo; D in registers.
// __launch_bounds__(256,3): >=3 waves/SIMD (reg cap ~170) to hide L2/LDS latency.
__global__ __launch_bounds__(256, 3) void cst_mlp_mfma(
    const float* __restrict__ r_cst,
    const __bf16* __restrict__ W1h, const __bf16* __restrict__ W1l,
    const float* __restrict__ b1,
    const __bf16* __restrict__ W2h, const __bf16* __restrict__ W2l,
    const float* __restrict__ g1, const float* __restrict__ bt1,
    float* __restrict__ m) {
  __shared__ __bf16 Ch[BM2][CPAD];   // 8.7 KB
  __shared__ __bf16 Cl[BM2][CPAD];   // 8.7 KB
  __shared__ float part_s[BM2][4];
  __shared__ float part_q[BM2][4];
  __shared__ float mu_s[BM2], rs_s[BM2];

  const int tid = threadIdx.x;
  const int wave = tid >> 6, lane = tid & 63;
  const long row0 = (long)blockIdx.x * BM2;

  const int fr = lane & 15;
  const int fkb = (lane >> 4) * 8;   // k offset within 32-wide kt tile
  const int rowb = (lane >> 4) * 4;  // C/D row base

  // A fragments straight from global (read-once, 32B/lane)
  bf16x8 a_hi[2][4], a_lo[2][4];
#pragma unroll
  for (int mt = 0; mt < 2; ++mt) {
    const float* arow = r_cst + (row0 + mt * 16 + fr) * H;
#pragma unroll
    for (int kt = 0; kt < 4; ++kt) split8(arow + kt * 32 + fkb, a_hi[mt][kt], a_lo[mt][kt]);
  }

  // GEMM1: C = relu(A@W1+b1); wave -> n-tiles {2w,2w+1}; split C into bf16 hi/lo in LDS
#pragma unroll
  for (int t = 0; t < 2; ++t) {
    const int nt = wave * 2 + t;
    f32x4 acc0 = {0.f, 0.f, 0.f, 0.f}, acc1 = {0.f, 0.f, 0.f, 0.f};
#pragma unroll
    for (int kt = 0; kt < 4; ++kt) {
      const long fi = (long)((nt * 4 + kt) * 64 + lane) * 8;
      bf16x8 bh = *(const bf16x8*)(W1h + fi);
      bf16x8 bl = *(const bf16x8*)(W1l + fi);
      acc0 = mfma16(a_hi[0][kt], bh, acc0);
      acc0 = mfma16(a_lo[0][kt], bh, acc0);
      acc0 = mfma16(a_hi[0][kt], bl, acc0);
      acc1 = mfma16(a_hi[1][kt], bh, acc1);
      acc1 = mfma16(a_lo[1][kt], bh, acc1);
      acc1 = mfma16(a_hi[1][kt], bl, acc1);
    }
    const int col = nt * 16 + fr;
    const float bb = b1[col];
#pragma unroll
    for (int r = 0; r < 4; ++r) {
      float v0 = fmaxf(acc0[r] + bb, 0.f);
      float v1 = fmaxf(acc1[r] + bb, 0.f);
      __bf16 h0 = (__bf16)v0, h1 = (__bf16)v1;
      Ch[rowb + r][col] = h0;
      Cl[rowb + r][col] = (__bf16)(v0 - (float)h0);
      Ch[16 + rowb + r][col] = h1;
      Cl[16 + rowb + r][col] = (__bf16)(v1 - (float)h1);
    }
  }
  __syncthreads();

  // GEMM2: D = C@W2 in registers; C frags re-read from LDS per nt (keeps regs low)
  f32x4 d[2][8];
  float ss[2][4], qq[2][4];
#pragma unroll
  for (int mt = 0; mt < 2; ++mt)
#pragma unroll
    for (int r = 0; r < 4; ++r) ss[mt][r] = qq[mt][r] = 0.f;

#pragma unroll
  for (int t = 0; t < 8; ++t) {
    const int nt = wave * 8 + t;
    f32x4 acc0 = {0.f, 0.f, 0.f, 0.f}, acc1 = {0.f, 0.f, 0.f, 0.f};
#pragma unroll
    for (int kt = 0; kt < 4; ++kt) {
      const long fi = (long)((nt * 4 + kt) * 64 + lane) * 8;
      bf16x8 bh = *(const bf16x8*)(W2h + fi);
      bf16x8 bl = *(const bf16x8*)(W2l + fi);
      bf16x8 ch0 = *(const bf16x8*)&Ch[fr][kt * 32 + fkb];
      bf16x8 cl0 = *(const bf16x8*)&Cl[fr][kt * 32 + fkb];
      bf16x8 ch1 = *(const bf16x8*)&Ch[16 + fr][kt * 32 + fkb];
      bf16x8 cl1 = *(const bf16x8*)&Cl[16 + fr][kt * 32 + fkb];
      acc0 = mfma16(ch0, bh, acc0);
      acc0 = mfma16(cl0, bh, acc0);
      acc0 = mfma16(ch0, bl, acc0);
      acc1 = mfma16(ch1, bh, acc1);
      acc1 = mfma16(cl1, bh, acc1);
      acc1 = mfma16(ch1, bl, acc1);
    }
    d[0][t] = acc0;
    d[1][t] = acc1;
#pragma unroll
    for (int r = 0; r < 4; ++r) {
      ss[0][r] += acc0[r];
      qq[0][r] += acc0[r] * acc0[r];
      ss[1][r] += acc1[r];
      qq[1][r] += acc1[r] * acc1[r];
    }
  }

  // reduce partials over the 16-lane fr-group
#pragma unroll
  for (int mt = 0; mt < 2; ++mt)
#pragma unroll
    for (int r = 0; r < 4; ++r) {
      float s = ss[mt][r], q = qq[mt][r];
#pragma unroll
      for (int off = 1; off < 16; off <<= 1) {
        s += __shfl_xor(s, off);
        q += __shfl_xor(q, off);
      }
      if (fr == 0) {
        part_s[mt * 16 + rowb + r][wave] = s;
        part_q[mt * 16 + rowb + r][wave] = q;
      }
    }
  __syncthreads();

  if (tid < BM2) {
    float s = part_s[tid][0] + part_s[tid][1] + part_s[tid][2] + part_s[tid][3];
    float q = part_q[tid][0] + part_q[tid][1] + part_q[tid][2] + part_q[tid][3];
    float mu = s * (1.f / H4);
    mu_s[tid] = mu;
    rs_s[tid] = rsqrtf(q * (1.f / H4) - mu * mu + 1e-5f);
  }
  __syncthreads();

  // normalize in registers, direct store (16-lane x 4B = 64B segments)
#pragma unroll
  for (int t = 0; t < 8; ++t) {
    const int col = (wave * 8 + t) * 16 + fr;
    const float g = g1[col], b = bt1[col];
#pragma unroll
    for (int mt = 0; mt < 2; ++mt) {
#pragma unroll
      for (int r = 0; r < 4; ++r) {
        const int row = mt * 16 + rowb + r;
        m[(row0 + row) * H4 + col] = (d[mt][t][r] - mu_s[row]) * rs_s[row] * g + b;
      }
    }
  }
}

// ---------------------------------------------------------------- val_rec MLP + LN(128) + residual, same structure
__global__ __launch_bounds__(256, 3) void val_mlp_mfma(
    const float* h, const float* __restrict__ x_val,
    const __bf16* __restrict__ W3h, const __bf16* __restrict__ W3l,
    const float* __restrict__ b3,
    const __bf16* __restrict__ W4h, const __bf16* __restrict__ W4l,
    const float* __restrict__ g2, const float* __restrict__ bt2,
    float* out) {
  __shared__ __bf16 Ch[BM2][CPAD];
  __shared__ __bf16 Cl[BM2][CPAD];
  __shared__ float part_s[BM2][4];
  __shared__ float part_q[BM2][4];
  __shared__ float mu_s[BM2], rs_s[BM2];

  const int tid = threadIdx.x;
  const int wave = tid >> 6, lane = tid & 63;
  const long row0 = (long)blockIdx.x * BM2;

  const int fr = lane & 15;
  const int fkb = (lane >> 4) * 8;
  const int rowb = (lane >> 4) * 4;

  bf16x8 a_hi[2][4], a_lo[2][4];
#pragma unroll
  for (int mt = 0; mt < 2; ++mt) {
    const float* arow = h + (row0 + mt * 16 + fr) * H;
#pragma unroll
    for (int kt = 0; kt < 4; ++kt) split8(arow + kt * 32 + fkb, a_hi[mt][kt], a_lo[mt][kt]);
  }

  // GEMM1: wave -> n-tiles {2w,2w+1}
#pragma unroll
  for (int t = 0; t < 2; ++t) {
    const int nt = wave * 2 + t;
    f32x4 acc0 = {0.f, 0.f, 0.f, 0.f}, acc1 = {0.f, 0.f, 0.f, 0.f};
#pragma unroll
    for (int kt = 0; kt < 4; ++kt) {
      const long fi = (long)((nt * 4 + kt) * 64 + lane) * 8;
      bf16x8 bh = *(const bf16x8*)(W3h + fi);
      bf16x8 bl = *(const bf16x8*)(W3l + fi);
      acc0 = mfma16(a_hi[0][kt], bh, acc0);
      acc0 = mfma16(a_lo[0][kt], bh, acc0);
      acc0 = mfma16(a_hi[0][kt], bl, acc0);
      acc1 = mfma16(a_hi[1][kt], bh, acc1);
      acc1 = mfma16(a_lo[1][kt], bh, acc1);
      acc1 = mfma16(a_hi[1][kt], bl, acc1);
    }
    const int col = nt * 16 + fr;
    const float bb = b3[col];
#pragma unroll
    for (int r = 0; r < 4; ++r) {
      float v0 = fmaxf(acc0[r] + bb, 0.f);
      float v1 = fmaxf(acc1[r] + bb, 0.f);
      __bf16 h0 = (__bf16)v0, h1 = (__bf16)v1;
      Ch[rowb + r][col] = h0;
      Cl[rowb + r][col] = (__bf16)(v0 - (float)h0);
      Ch[16 + rowb + r][col] = h1;
      Cl[16 + rowb + r][col] = (__bf16)(v1 - (float)h1);
    }
  }
  __syncthreads();

  // GEMM2: wave -> n-tiles {2w,2w+1}; D in registers
  f32x4 d[2][2];
  float ss[2][4], qq[2][4];
#pragma unroll
  for (int mt = 0; mt < 2; ++mt)
#pragma unroll
    for (int r = 0; r < 4; ++r) ss[mt][r] = qq[mt][r] = 0.f;

#pragma unroll
  for (int t = 0; t < 2; ++t) {
    const int nt = wave * 2 + t;
    f32x4 acc0 = {0.f, 0.f, 0.f, 0.f}, acc1 = {0.f, 0.f, 0.f, 0.f};
#pragma unroll
    for (int kt = 0; kt < 4; ++kt) {
      const long fi = (long)((nt * 4 + kt) * 64 + lane) * 8;
      bf16x8 bh = *(const bf16x8*)(W4h + fi);
      bf16x8 bl = *(const bf16x8*)(W4l + fi);
      bf16x8 ch0 = *(const bf16x8*)&Ch[fr][kt * 32 + fkb];
      bf16x8 cl0 = *(const bf16x8*)&Cl[fr][kt * 32 + fkb];
      bf16x8 ch1 = *(const bf16x8*)&Ch[16 + fr][kt * 32 + fkb];
      bf16x8 cl1 = *(const bf16x8*)&Cl[16 + fr][kt * 32 + fkb];
      acc0 = mfma16(ch0, bh, acc0);
      acc0 = mfma16(cl0, bh, acc0);
      acc0 = mfma16(ch0, bl, acc0);
      acc1 = mfma16(ch1, bh, acc1);
      acc1 = mfma16(cl1, bh, acc1);
      acc1 = mfma16(ch1, bl, acc1);
    }
    d[0][t] = acc0;
    d[1][t] = acc1;
#pragma unroll
    for (int r = 0; r < 4; ++r) {
      ss[0][r] += acc0[r];
      qq[0][r] += acc0[r] * acc0[r];
      ss[1][r] += acc1[r];
      qq[1][r] += acc1[r] * acc1[r];
    }
  }

#pragma unroll
  for (int mt = 0; mt < 2; ++mt)
#pragma unroll
    for (int r = 0; r < 4; ++r) {
      float s = ss[mt][r], q = qq[mt][r];
#pragma unroll
      for (int off = 1; off < 16; off <<= 1) {
        s += __shfl_xor(s, off);
        q += __shfl_xor(q, off);
      }
      if (fr == 0) {
        part_s[mt * 16 + rowb + r][wave] = s;
        part_q[mt * 16 + rowb + r][wave] = q;
      }
    }
  __syncthreads();

  if (tid < BM2) {
    float s = part_s[tid][0] + part_s[tid][1] + part_s[tid][2] + part_s[tid][3];
    float q = part_q[tid][0] + part_q[tid][1] + part_q[tid][2] + part_q[tid][3];
    float mu = s * (1.f / H);
    mu_s[tid] = mu;
    rs_s[tid] = rsqrtf(q * (1.f / H) - mu * mu + 1e-5f);
  }
  __syncthreads();

#pragma unroll
  for (int t = 0; t < 2; ++t) {
    const int col = (wave * 2 + t) * 16 + fr;
    const float g = g2[col], b = bt2[col];
#pragma unroll
    for (int mt = 0; mt < 2; ++mt) {
#pragma unroll
      for (int r = 0; r < 4; ++r) {
        const int row = mt * 16 + rowb + r;
        const float xv = x_val[(row0 + row) * H + col];
        out[(row0 + row) * H + col] = (d[mt][t][r] - mu_s[row]) * rs_s[row] * g + b + xv;
      }
    }
  }
}

// ---------------------------------------------------------------- fp32 fallback MLPs
__global__ __launch_bounds__(256) void cst_mlp_kernel(
    const float* __restrict__ r_cst,
    const float* __restrict__ W1, const float* __restrict__ b1,
    const float* __restrict__ W2, const float* __restrict__ g1,
    const float* __restrict__ bt1, float* __restrict__ m) {
  __shared__ float As[BM][H];
  __shared__ float Cs[BM][H];
  __shared__ float Ds[BM][H4];
  __shared__ float mu_s[BM], rs_s[BM];
  const int tid = threadIdx.x;
  const long row0 = (long)blockIdx.x * BM;
  {
    const float4* src = (const float4*)(r_cst + row0 * H);
    float4* dst = (float4*)&As[0][0];
#pragma unroll
    for (int i = 0; i < 2; ++i) dst[tid + i * 256] = src[tid + i * 256];
  }
  __syncthreads();
  {
    const int j = tid & (H - 1);
    const int r0 = (tid >> 7) * 8;
    float acc[8] = {0, 0, 0, 0, 0, 0, 0, 0};
#pragma unroll 4
    for (int k = 0; k < H; ++k) {
      float w = W1[k * H + j];
#pragma unroll
      for (int r = 0; r < 8; ++r) acc[r] = fmaf(As[r0 + r][k], w, acc[r]);
    }
    float bb = b1[j];
#pragma unroll
    for (int r = 0; r < 8; ++r) Cs[r0 + r][j] = fmaxf(acc[r] + bb, 0.f);
  }
  __syncthreads();
  {
    const int j = tid * 2;
    float acc[BM][2];
#pragma unroll
    for (int r = 0; r < BM; ++r) acc[r][0] = acc[r][1] = 0.f;
    for (int k = 0; k < H; k += 4) {
      float4 c[BM];
#pragma unroll
      for (int r = 0; r < BM; ++r) c[r] = *(const float4*)&Cs[r][k];
#pragma unroll
      for (int kk = 0; kk < 4; ++kk) {
        const float2 w = *(const float2*)&W2[(k + kk) * H4 + j];
#pragma unroll
        for (int r = 0; r < BM; ++r) {
          float cv = (&c[r].x)[kk];
          acc[r][0] = fmaf(cv, w.x, acc[r][0]);
          acc[r][1] = fmaf(cv, w.y, acc[r][1]);
        }
      }
    }
#pragma unroll
    for (int r = 0; r < BM; ++r) {
      Ds[r][j] = acc[r][0];
      Ds[r][j + 1] = acc[r][1];
    }
  }
  __syncthreads();
  {
    const int wv = tid >> 6, lane = tid & 63;
    for (int r = wv * 4; r < wv * 4 + 4; ++r) {
      float s = 0.f, q = 0.f;
      const float4* rowp = (const float4*)&Ds[r][0];
#pragma unroll
      for (int i = 0; i < 2; ++i) {
        float4 v = rowp[lane * 2 + i];
        s += v.x + v.y + v.z + v.w;
        q += v.x * v.x + v.y * v.y + v.z * v.z + v.w * v.w;
      }
#pragma unroll
      for (int off = 32; off; off >>= 1) {
        s += __shfl_xor(s, off);
        q += __shfl_xor(q, off);
      }
      if (lane == 0) {
        float mu = s * (1.f / H4);
        mu_s[r] = mu;
        rs_s[r] = rsqrtf(q * (1.f / H4) - mu * mu + 1e-5f);
      }
    }
  }
  __syncthreads();
  {
    float4* out4 = (float4*)(m + row0 * H4);
    const float4* D4 = (const float4*)&Ds[0][0];
    const float4* g4 = (const float4*)g1;
    const float4* b4 = (const float4*)bt1;
#pragma unroll
    for (int it = 0; it < 8; ++it) {
      int e4 = tid + it * 256;
      int r = e4 >> 7;
      int c4 = e4 & 127;
      float4 v = D4[e4];
      float4 g = g4[c4], b = b4[c4];
      float mu = mu_s[r], rs = rs_s[r];
      float4 o;
      o.x = (v.x - mu) * rs * g.x + b.x;
      o.y = (v.y - mu) * rs * g.y + b.y;
      o.z = (v.z - mu) * rs * g.z + b.z;
      o.w = (v.w - mu) * rs * g.w + b.w;
      out4[e4] = o;
    }
  }
}

__global__ __launch_bounds__(256) void val_mlp_kernel(
    const float* h, const float* __restrict__ x_val,
    const float* __restrict__ W3, const float* __restrict__ b3,
    const float* __restrict__ W4, const float* __restrict__ g2,
    const float* __restrict__ bt2, float* out) {
  __shared__ float As[BM][H];
  __shared__ float Cs[BM][H];
  __shared__ float Ds[BM][H];
  __shared__ float mu_s[BM], rs_s[BM];
  const int tid = threadIdx.x;
  const long row0 = (long)blockIdx.x * BM;
  {
    const float4* src = (const float4*)(h + row0 * H);
    float4* dst = (float4*)&As[0][0];
#pragma unroll
    for (int i = 0; i < 2; ++i) dst[tid + i * 256] = src[tid + i * 256];
  }
  __syncthreads();
  const int j = tid & (H - 1);
  const int r0 = (tid >> 7) * 8;
  {
    float acc[8] = {0, 0, 0, 0, 0, 0, 0, 0};
#pragma unroll 4
    for (int k = 0; k < H; ++k) {
      float w = W3[k * H + j];
#pragma unroll
      for (int r = 0; r < 8; ++r) acc[r] = fmaf(As[r0 + r][k], w, acc[r]);
    }
    float bb = b3[j];
#pragma unroll
    for (int r = 0; r < 8; ++r) Cs[r0 + r][j] = fmaxf(acc[r] + bb, 0.f);
  }
  __syncthreads();
  {
    float acc[8] = {0, 0, 0, 0, 0, 0, 0, 0};
#pragma unroll 4
    for (int k = 0; k < H; ++k) {
      float w = W4[k * H + j];
#pragma unroll
      for (int r = 0; r < 8; ++r) acc[r] = fmaf(Cs[r0 + r][k], w, acc[r]);
    }
#pragma unroll
    for (int r = 0; r < 8; ++r) Ds[r0 + r][j] = acc[r];
  }
  __syncthreads();
  {
    const int wv = tid >> 6, lane = tid & 63;
    for (int r = wv * 4; r < wv * 4 + 4; ++r) {
      float2 v = *(const float2*)&Ds[r][lane * 2];
      float s = v.x + v.y, q = v.x * v.x + v.y * v.y;
#pragma unroll
      for (int off = 32; off; off >>= 1) {
        s += __shfl_xor(s, off);
        q += __shfl_xor(q, off);
      }
      if (lane == 0) {
        float mu = s * (1.f / H);
        mu_s[r] = mu;
        rs_s[r] = rsqrtf(q * (1.f / H) - mu * mu + 1e-5f);
      }
    }
  }
  __syncthreads();
  {
    float4* out4 = (float4*)(out + row0 * H);
    const float4* x4 = (const float4*)(x_val + row0 * H);
    const float4* D4 = (const float4*)&Ds[0][0];
    const float4* g4 = (const float4*)g2;
    const float4* b4 = (const float4*)bt2;
#pragma unroll
    for (int it = 0; it < 2; ++it) {
      int e4 = tid + it * 256;
      int r = e4 >> 5;
      int c4 = e4 & 31;
      float4 v = D4[e4];
      float4 g = g4[c4], b = b4[c4], xv = x4[e4];
      float mu = mu_s[r], rs = rs_s[r];
      float4 o;
      o.x = (v.x - mu) * rs * g.x + b.x + xv.x;
      o.y = (v.y - mu) * rs * g.y + b.y + xv.y;
      o.z = (v.z - mu) * rs * g.z + b.z + xv.z;
      o.w = (v.w - mu) * rs * g.w + b.w + xv.w;
      out4[e4] = o;
    }
  }
}

// ---------------------------------------------------------------- CSR build
__global__ __launch_bounds__(256) void count_kernel(const int* __restrict__ e_in,
                                                    int* __restrict__ cnt, int nE) {
  int i = blockIdx.x * 256 + threadIdx.x;
  if (i < nE) atomicAdd(&cnt[e_in[i]], 1);
}

__device__ inline int wave_incl_scan(int x) {
#pragma unroll
  for (int off = 1; off < 64; off <<= 1) {
    int y = __shfl_up(x, off);
    if ((threadIdx.x & 63) >= off) x += y;
  }
  return x;
}

__global__ __launch_bounds__(256) void scan1_kernel(const int* __restrict__ cnt,
                                                    int* __restrict__ offs,
                                                    int* __restrict__ bsums, int n) {
  int i = blockIdx.x * 256 + threadIdx.x;
  int v = (i < n) ? cnt[i] : 0;
  int incl = wave_incl_scan(v);
  __shared__ int wsum[4];
  int wv = threadIdx.x >> 6, lane = threadIdx.x & 63;
  if (lane == 63) wsum[wv] = incl;
  __syncthreads();
  int add = 0;
  for (int w = 0; w < wv; ++w) add += wsum[w];
  if (i < n) offs[i] = incl - v + add;
  if (threadIdx.x == 255) bsums[blockIdx.x] = incl + add;
}

__global__ __launch_bounds__(1024) void scan2_kernel(int* __restrict__ bsums, int nb,
                                                     int* __restrict__ offs, int n, int total) {
  __shared__ int s[1024];
  int t = threadIdx.x;
  int orig = (t < nb) ? bsums[t] : 0;
  s[t] = orig;
  __syncthreads();
  for (int off = 1; off < 1024; off <<= 1) {
    int v = (t >= off) ? s[t - off] : 0;
    __syncthreads();
    s[t] += v;
    __syncthreads();
  }
  if (t < nb) bsums[t] = s[t] - orig;
  if (t == 0) offs[n] = total;
}

__global__ __launch_bounds__(256) void scan3_kernel(int* __restrict__ offs,
                                                    const int* __restrict__ bsums, int n) {
  int i = blockIdx.x * 256 + threadIdx.x;
  if (i < n) offs[i] += bsums[blockIdx.x];
}

__global__ __launch_bounds__(256) void fill_kernel(
    const int* __restrict__ e_out, const int* __restrict__ e_in,
    const int* __restrict__ LE, const int* __restrict__ PE,
    const int* __restrict__ offs, int* __restrict__ cnt2,
    int* __restrict__ msg_row, int nE) {
  int e = blockIdx.x * 256 + threadIdx.x;
  if (e >= nE) return;
  int v = e_in[e];
  int pos = offs[v] + atomicAdd(&cnt2[v], 1);
  msg_row[pos] = 4 * e_out[e] + 2 * LE[e] + PE[e];
}

// ---------------------------------------------------------------- gather-reduce: h = x_val + sum(msgs)
// one wave per value row; two half-waves each cover the 128-float row with float4 lanes,
// processing interleaved msg indices (2 rows in flight, 2x unroll -> 4 loads outstanding).
__global__ __launch_bounds__(256) void gather_kernel(
    const float* __restrict__ m, const float* __restrict__ x_val,
    const int* __restrict__ offs, const int* __restrict__ msg_row,
    float* __restrict__ h, int nv) {
  int v = blockIdx.x * 4 + (threadIdx.x >> 6);
  if (v >= nv) return;
  int lane = threadIdx.x & 63;
  int half = lane >> 5, li = lane & 31;
  int beg = offs[v], end = offs[v + 1];
  float4 acc = {0.f, 0.f, 0.f, 0.f};
  int p = beg + half;
  for (; p + 2 < end; p += 4) {
    int r0 = msg_row[p];
    int r1 = msg_row[p + 2];
    float4 a = *(const float4*)(m + (long)r0 * H + li * 4);
    float4 b = *(const float4*)(m + (long)r1 * H + li * 4);
    acc.x += a.x + b.x;
    acc.y += a.y + b.y;
    acc.z += a.z + b.z;
    acc.w += a.w + b.w;
  }
  if (p < end) {
    int r0 = msg_row[p];
    float4 a = *(const float4*)(m + (long)r0 * H + li * 4);
    acc.x += a.x;
    acc.y += a.y;
    acc.z += a.z;
    acc.w += a.w;
  }
  // combine the two halves (lane i <-> lane i+32 hold same columns)
  acc.x += __shfl_xor(acc.x, 32);
  acc.y += __shfl_xor(acc.y, 32);
  acc.z += __shfl_xor(acc.z, 32);
  acc.w += __shfl_xor(acc.w, 32);
  if (half == 0) {
    float4 xv = *(const float4*)(x_val + (long)v * H + li * 4);
    acc.x += xv.x;
    acc.y += xv.y;
    acc.z += xv.z;
    acc.w += xv.w;
    *(float4*)(h + (long)v * H + li * 4) = acc;
  }
}

// ---------------------------------------------------------------- fallback atomic scatter
__global__ __launch_bounds__(256) void scatter_kernel(
    const float* __restrict__ m, const int* __restrict__ e_out,
    const int* __restrict__ e_in, const int* __restrict__ LE,
    const int* __restrict__ PE, float* h, int nE) {
  int t = blockIdx.x * 256 + threadIdx.x;
  int edge = t >> 5;
  if (edge >= nE) return;
  int lane = t & 31;
  int c0 = e_out[edge];
  int c1 = e_in[edge];
  int oi = 4 * c0 + 2 * LE[edge] + PE[edge];
  float4 v = *(const float4*)(m + (long)oi * H + lane * 4);
  float* dst = h + (long)c1 * H + lane * 4;
  unsafeAtomicAdd(dst + 0, v.x);
  unsafeAtomicAdd(dst + 1, v.y);
  unsafeAtomicAdd(dst + 2, v.z);
  unsafeAtomicAdd(dst + 3, v.w);
}

extern "C" void kernel_launch(void* const* d_in, const int* in_sizes, int n_in,
                              void* d_out, int out_size, void* d_ws, size_t ws_size,
                              hipStream_t stream) {
  const float* x_val = (const float*)d_in[0];
  const float* r_cst = (const float*)d_in[1];
  const int* edges  = (const int*)d_in[2];   // [2, E]
  const int* LE     = (const int*)d_in[3];
  const int* PE     = (const int*)d_in[4];
  const float* W1  = (const float*)d_in[7];
  const float* b1  = (const float*)d_in[8];
  const float* W2  = (const float*)d_in[9];
  const float* g1  = (const float*)d_in[10];
  const float* bt1 = (const float*)d_in[11];
  const float* W3  = (const float*)d_in[12];
  const float* b3  = (const float*)d_in[13];
  const float* W4  = (const float*)d_in[14];
  const float* g2  = (const float*)d_in[15];
  const float* bt2 = (const float*)d_in[16];

  const int NV = in_sizes[0] / H;
  const int NC = in_sizes[1] / H;
  const int nE = in_sizes[3];

  float* out  = (float*)d_out;
  float* mbuf = (float*)d_ws;                         // 4*NC*H floats

  const size_t mbytes = (size_t)4 * NC * H * sizeof(float);
  int* offs  = (int*)((char*)d_ws + mbytes);          // NV+1
  int* cnt   = offs + (NV + 1);                       // NV
  int* cnt2  = cnt + NV;                              // NV
  int* bsums = cnt2 + NV;                             // up to 1024
  int* msg_row = bsums + 1024;                        // nE
  const size_t csr_bytes = ((size_t)(NV + 1) + NV + NV + 1024 + nE) * sizeof(int);
  const size_t need_csr = mbytes + csr_bytes;

  // weight packs (hi/lo bf16 fragments) after CSR arrays, 64B aligned
  const size_t pack_off = (need_csr + 63) & ~(size_t)63;
  __bf16* W1h = (__bf16*)((char*)d_ws + pack_off);
  __bf16* W1l = W1h + 16384;
  __bf16* W2h = W1l + 16384;
  __bf16* W2l = W2h + 65536;
  __bf16* W3h = W2l + 65536;
  __bf16* W3l = W3h + 16384;
  __bf16* W4h = W3l + 16384;
  __bf16* W4l = W4h + 16384;
  const size_t need_mfma = pack_off + (size_t)(2 * (16384 * 3 + 65536)) * sizeof(__bf16);

  const int nb = (NV + 255) / 256;
  const bool csr_ok = (ws_size >= need_csr) && (nb <= 1024);
  const bool mfma_ok = csr_ok && (ws_size >= need_mfma) && (NC % BM2 == 0) && (NV % BM2 == 0);

  if (mfma_ok) {
    pack_kernel<<<8, 256, 0, stream>>>(W1, H, H, W1h, W1l);
    pack_kernel<<<32, 256, 0, stream>>>(W2, H, H4, W2h, W2l);
    pack_kernel<<<8, 256, 0, stream>>>(W3, H, H, W3h, W3l);
    pack_kernel<<<8, 256, 0, stream>>>(W4, H, H, W4h, W4l);
    cst_mlp_mfma<<<NC / BM2, 256, 0, stream>>>(r_cst, W1h, W1l, b1, W2h, W2l, g1, bt1, mbuf);
  } else {
    cst_mlp_kernel<<<NC / BM, 256, 0, stream>>>(r_cst, W1, b1, W2, g1, bt1, mbuf);
  }

  if (csr_ok) {
    hipMemsetAsync(cnt, 0, (size_t)NV * sizeof(int), stream);
    hipMemsetAsync(cnt2, 0, (size_t)NV * sizeof(int), stream);
    count_kernel<<<(nE + 255) / 256, 256, 0, stream>>>(edges + nE, cnt, nE);
    scan1_kernel<<<nb, 256, 0, stream>>>(cnt, offs, bsums, NV);
    scan2_kernel<<<1, 1024, 0, stream>>>(bsums, nb, offs, NV, nE);
    scan3_kernel<<<nb, 256, 0, stream>>>(offs, bsums, NV);
    fill_kernel<<<(nE + 255) / 256, 256, 0, stream>>>(edges, edges + nE, LE, PE, offs, cnt2,
                                                      msg_row, nE);
    gather_kernel<<<(NV + 3) / 4, 256, 0, stream>>>(mbuf, x_val, offs, msg_row, out, NV);
  } else {
    copy_kernel<<<2048, 256, 0, stream>>>((const float4*)x_val, (float4*)out, NV * H / 4);
    scatter_kernel<<<(nE * 32 + 255) / 256, 256, 0, stream>>>(mbuf, edges, edges + nE, LE, PE,
                                                              out, nE);
  }

  if (mfma_ok) {
    val_mlp_mfma<<<NV / BM2, 256, 0, stream>>>(out, x_val, W3h, W3l, b3, W4h, W4l, g2, bt2, out);
  } else {
    val_mlp_kernel<<<NV / BM, 256, 0, stream>>>(out, x_val, W3, b3, W4, g2, bt2, out);
  }
}

// Round 9
// 589.436 us; speedup vs baseline: 5.5545x; 1.0785x over previous
//
#include <hip/hip_runtime.h>
#include <hip/hip_bf16.h>
#include <hip/hip_fp16.h>

#define H 128
#define H4 512
#define BM 16   // fallback fp32 kernels
#define BM2 32  // MFMA kernels
#define CPAD 136  // 128 + 8 bf16 pad

typedef __bf16 bf16x8 __attribute__((ext_vector_type(8)));
typedef float f32x4 __attribute__((ext_vector_type(4)));
typedef _Float16 half4 __attribute__((ext_vector_type(4)));

__device__ inline f32x4 mfma16(bf16x8 a, bf16x8 b, f32x4 c) {
  return __builtin_amdgcn_mfma_f32_16x16x32_bf16(a, b, c, 0, 0, 0);
}

// ---------------------------------------------------------------- weight pack: fp32 [K][N] -> hi/lo bf16 MFMA B-fragments
__global__ __launch_bounds__(256) void pack_kernel(const float* __restrict__ W, int K, int N,
                                                   __bf16* __restrict__ hi,
                                                   __bf16* __restrict__ lo) {
  int idx = blockIdx.x * 256 + threadIdx.x;
  int total = (N >> 4) * (K >> 5) * 64;
  if (idx >= total) return;
  int lane = idx & 63;
  int tile = idx >> 6;
  int KT = K >> 5;
  int nt = tile / KT, kt = tile - nt * KT;
  int col = nt * 16 + (lane & 15);
  int k0 = kt * 32 + (lane >> 4) * 8;
#pragma unroll
  for (int i = 0; i < 8; ++i) {
    float x = W[(long)(k0 + i) * N + col];
    __bf16 h = (__bf16)x;
    hi[(long)idx * 8 + i] = h;
    lo[(long)idx * 8 + i] = (__bf16)(x - (float)h);
  }
}

// ---------------------------------------------------------------- copy (fallback path only)
__global__ __launch_bounds__(256) void copy_kernel(const float4* __restrict__ src,
                                                   float4* __restrict__ dst, int n4) {
  int i = blockIdx.x * 256 + threadIdx.x;
  int stride = gridDim.x * 256;
  for (; i < n4; i += stride) dst[i] = src[i];
}

// ---------------------------------------------------------------- helpers
__device__ inline void split8(const float* p, bf16x8& hi, bf16x8& lo) {
  float4 u = *(const float4*)p, v = *(const float4*)(p + 4);
  float vals[8] = {u.x, u.y, u.z, u.w, v.x, v.y, v.z, v.w};
#pragma unroll
  for (int i = 0; i < 8; ++i) {
    __bf16 hh = (__bf16)vals[i];
    hi[i] = hh;
    lo[i] = (__bf16)(vals[i] - (float)hh);
  }
}

// ---------------------------------------------------------------- cst_send MLP + LN(512), MFMA split-bf16
// A frags direct from global; C staged in LDS as bf16 hi/lo; D in regs; m stored FP16 (halves gather bytes).
__global__ __launch_bounds__(256, 3) void cst_mlp_mfma(
    const float* __restrict__ r_cst,
    const __bf16* __restrict__ W1h, const __bf16* __restrict__ W1l,
    const float* __restrict__ b1,
    const __bf16* __restrict__ W2h, const __bf16* __restrict__ W2l,
    const float* __restrict__ g1, const float* __restrict__ bt1,
    _Float16* __restrict__ m) {
  __shared__ __bf16 Ch[BM2][CPAD];
  __shared__ __bf16 Cl[BM2][CPAD];
  __shared__ float part_s[BM2][4];
  __shared__ float part_q[BM2][4];
  __shared__ float mu_s[BM2], rs_s[BM2];

  const int tid = threadIdx.x;
  const int wave = tid >> 6, lane = tid & 63;
  const long row0 = (long)blockIdx.x * BM2;

  const int fr = lane & 15;
  const int fkb = (lane >> 4) * 8;
  const int rowb = (lane >> 4) * 4;

  // A fragments straight from global (read-once, 32B/lane)
  bf16x8 a_hi[2][4], a_lo[2][4];
#pragma unroll
  for (int mt = 0; mt < 2; ++mt) {
    const float* arow = r_cst + (row0 + mt * 16 + fr) * H;
#pragma unroll
    for (int kt = 0; kt < 4; ++kt) split8(arow + kt * 32 + fkb, a_hi[mt][kt], a_lo[mt][kt]);
  }

  // GEMM1: C = relu(A@W1+b1)
#pragma unroll
  for (int t = 0; t < 2; ++t) {
    const int nt = wave * 2 + t;
    f32x4 acc0 = {0.f, 0.f, 0.f, 0.f}, acc1 = {0.f, 0.f, 0.f, 0.f};
#pragma unroll
    for (int kt = 0; kt < 4; ++kt) {
      const long fi = (long)((nt * 4 + kt) * 64 + lane) * 8;
      bf16x8 bh = *(const bf16x8*)(W1h + fi);
      bf16x8 bl = *(const bf16x8*)(W1l + fi);
      acc0 = mfma16(a_hi[0][kt], bh, acc0);
      acc0 = mfma16(a_lo[0][kt], bh, acc0);
      acc0 = mfma16(a_hi[0][kt], bl, acc0);
      acc1 = mfma16(a_hi[1][kt], bh, acc1);
      acc1 = mfma16(a_lo[1][kt], bh, acc1);
      acc1 = mfma16(a_hi[1][kt], bl, acc1);
    }
    const int col = nt * 16 + fr;
    const float bb = b1[col];
#pragma unroll
    for (int r = 0; r < 4; ++r) {
      float v0 = fmaxf(acc0[r] + bb, 0.f);
      float v1 = fmaxf(acc1[r] + bb, 0.f);
      __bf16 h0 = (__bf16)v0, h1 = (__bf16)v1;
      Ch[rowb + r][col] = h0;
      Cl[rowb + r][col] = (__bf16)(v0 - (float)h0);
      Ch[16 + rowb + r][col] = h1;
      Cl[16 + rowb + r][col] = (__bf16)(v1 - (float)h1);
    }
  }
  __syncthreads();

  // GEMM2: D = C@W2 in registers; C frags re-read from LDS per nt
  f32x4 d[2][8];
  float ss[2][4], qq[2][4];
#pragma unroll
  for (int mt = 0; mt < 2; ++mt)
#pragma unroll
    for (int r = 0; r < 4; ++r) ss[mt][r] = qq[mt][r] = 0.f;

#pragma unroll
  for (int t = 0; t < 8; ++t) {
    const int nt = wave * 8 + t;
    f32x4 acc0 = {0.f, 0.f, 0.f, 0.f}, acc1 = {0.f, 0.f, 0.f, 0.f};
#pragma unroll
    for (int kt = 0; kt < 4; ++kt) {
      const long fi = (long)((nt * 4 + kt) * 64 + lane) * 8;
      bf16x8 bh = *(const bf16x8*)(W2h + fi);
      bf16x8 bl = *(const bf16x8*)(W2l + fi);
      bf16x8 ch0 = *(const bf16x8*)&Ch[fr][kt * 32 + fkb];
      bf16x8 cl0 = *(const bf16x8*)&Cl[fr][kt * 32 + fkb];
      bf16x8 ch1 = *(const bf16x8*)&Ch[16 + fr][kt * 32 + fkb];
      bf16x8 cl1 = *(const bf16x8*)&Cl[16 + fr][kt * 32 + fkb];
      acc0 = mfma16(ch0, bh, acc0);
      acc0 = mfma16(cl0, bh, acc0);
      acc0 = mfma16(ch0, bl, acc0);
      acc1 = mfma16(ch1, bh, acc1);
      acc1 = mfma16(cl1, bh, acc1);
      acc1 = mfma16(ch1, bl, acc1);
    }
    d[0][t] = acc0;
    d[1][t] = acc1;
#pragma unroll
    for (int r = 0; r < 4; ++r) {
      ss[0][r] += acc0[r];
      qq[0][r] += acc0[r] * acc0[r];
      ss[1][r] += acc1[r];
      qq[1][r] += acc1[r] * acc1[r];
    }
  }

#pragma unroll
  for (int mt = 0; mt < 2; ++mt)
#pragma unroll
    for (int r = 0; r < 4; ++r) {
      float s = ss[mt][r], q = qq[mt][r];
#pragma unroll
      for (int off = 1; off < 16; off <<= 1) {
        s += __shfl_xor(s, off);
        q += __shfl_xor(q, off);
      }
      if (fr == 0) {
        part_s[mt * 16 + rowb + r][wave] = s;
        part_q[mt * 16 + rowb + r][wave] = q;
      }
    }
  __syncthreads();

  if (tid < BM2) {
    float s = part_s[tid][0] + part_s[tid][1] + part_s[tid][2] + part_s[tid][3];
    float q = part_q[tid][0] + part_q[tid][1] + part_q[tid][2] + part_q[tid][3];
    float mu = s * (1.f / H4);
    mu_s[tid] = mu;
    rs_s[tid] = rsqrtf(q * (1.f / H4) - mu * mu + 1e-5f);
  }
  __syncthreads();

  // normalize in registers, store fp16 (16-lane x 2B = 32B segments)
#pragma unroll
  for (int t = 0; t < 8; ++t) {
    const int col = (wave * 8 + t) * 16 + fr;
    const float g = g1[col], b = bt1[col];
#pragma unroll
    for (int mt = 0; mt < 2; ++mt) {
#pragma unroll
      for (int r = 0; r < 4; ++r) {
        const int row = mt * 16 + rowb + r;
        m[(row0 + row) * H4 + col] = (_Float16)((d[mt][t][r] - mu_s[row]) * rs_s[row] * g + b);
      }
    }
  }
}

// ---------------------------------------------------------------- val_rec MLP + LN(128) + residual
__global__ __launch_bounds__(256, 3) void val_mlp_mfma(
    const float* h, const float* __restrict__ x_val,
    const __bf16* __restrict__ W3h, const __bf16* __restrict__ W3l,
    const float* __restrict__ b3,
    const __bf16* __restrict__ W4h, const __bf16* __restrict__ W4l,
    const float* __restrict__ g2, const float* __restrict__ bt2,
    float* out) {
  __shared__ __bf16 Ch[BM2][CPAD];
  __shared__ __bf16 Cl[BM2][CPAD];
  __shared__ float part_s[BM2][4];
  __shared__ float part_q[BM2][4];
  __shared__ float mu_s[BM2], rs_s[BM2];

  const int tid = threadIdx.x;
  const int wave = tid >> 6, lane = tid & 63;
  const long row0 = (long)blockIdx.x * BM2;

  const int fr = lane & 15;
  const int fkb = (lane >> 4) * 8;
  const int rowb = (lane >> 4) * 4;

  bf16x8 a_hi[2][4], a_lo[2][4];
#pragma unroll
  for (int mt = 0; mt < 2; ++mt) {
    const float* arow = h + (row0 + mt * 16 + fr) * H;
#pragma unroll
    for (int kt = 0; kt < 4; ++kt) split8(arow + kt * 32 + fkb, a_hi[mt][kt], a_lo[mt][kt]);
  }

#pragma unroll
  for (int t = 0; t < 2; ++t) {
    const int nt = wave * 2 + t;
    f32x4 acc0 = {0.f, 0.f, 0.f, 0.f}, acc1 = {0.f, 0.f, 0.f, 0.f};
#pragma unroll
    for (int kt = 0; kt < 4; ++kt) {
      const long fi = (long)((nt * 4 + kt) * 64 + lane) * 8;
      bf16x8 bh = *(const bf16x8*)(W3h + fi);
      bf16x8 bl = *(const bf16x8*)(W3l + fi);
      acc0 = mfma16(a_hi[0][kt], bh, acc0);
      acc0 = mfma16(a_lo[0][kt], bh, acc0);
      acc0 = mfma16(a_hi[0][kt], bl, acc0);
      acc1 = mfma16(a_hi[1][kt], bh, acc1);
      acc1 = mfma16(a_lo[1][kt], bh, acc1);
      acc1 = mfma16(a_hi[1][kt], bl, acc1);
    }
    const int col = nt * 16 + fr;
    const float bb = b3[col];
#pragma unroll
    for (int r = 0; r < 4; ++r) {
      float v0 = fmaxf(acc0[r] + bb, 0.f);
      float v1 = fmaxf(acc1[r] + bb, 0.f);
      __bf16 h0 = (__bf16)v0, h1 = (__bf16)v1;
      Ch[rowb + r][col] = h0;
      Cl[rowb + r][col] = (__bf16)(v0 - (float)h0);
      Ch[16 + rowb + r][col] = h1;
      Cl[16 + rowb + r][col] = (__bf16)(v1 - (float)h1);
    }
  }
  __syncthreads();

  f32x4 d[2][2];
  float ss[2][4], qq[2][4];
#pragma unroll
  for (int mt = 0; mt < 2; ++mt)
#pragma unroll
    for (int r = 0; r < 4; ++r) ss[mt][r] = qq[mt][r] = 0.f;

#pragma unroll
  for (int t = 0; t < 2; ++t) {
    const int nt = wave * 2 + t;
    f32x4 acc0 = {0.f, 0.f, 0.f, 0.f}, acc1 = {0.f, 0.f, 0.f, 0.f};
#pragma unroll
    for (int kt = 0; kt < 4; ++kt) {
      const long fi = (long)((nt * 4 + kt) * 64 + lane) * 8;
      bf16x8 bh = *(const bf16x8*)(W4h + fi);
      bf16x8 bl = *(const bf16x8*)(W4l + fi);
      bf16x8 ch0 = *(const bf16x8*)&Ch[fr][kt * 32 + fkb];
      bf16x8 cl0 = *(const bf16x8*)&Cl[fr][kt * 32 + fkb];
      bf16x8 ch1 = *(const bf16x8*)&Ch[16 + fr][kt * 32 + fkb];
      bf16x8 cl1 = *(const bf16x8*)&Cl[16 + fr][kt * 32 + fkb];
      acc0 = mfma16(ch0, bh, acc0);
      acc0 = mfma16(cl0, bh, acc0);
      acc0 = mfma16(ch0, bl, acc0);
      acc1 = mfma16(ch1, bh, acc1);
      acc1 = mfma16(cl1, bh, acc1);
      acc1 = mfma16(ch1, bl, acc1);
    }
    d[0][t] = acc0;
    d[1][t] = acc1;
#pragma unroll
    for (int r = 0; r < 4; ++r) {
      ss[0][r] += acc0[r];
      qq[0][r] += acc0[r] * acc0[r];
      ss[1][r] += acc1[r];
      qq[1][r] += acc1[r] * acc1[r];
    }
  }

#pragma unroll
  for (int mt = 0; mt < 2; ++mt)
#pragma unroll
    for (int r = 0; r < 4; ++r) {
      float s = ss[mt][r], q = qq[mt][r];
#pragma unroll
      for (int off = 1; off < 16; off <<= 1) {
        s += __shfl_xor(s, off);
        q += __shfl_xor(q, off);
      }
      if (fr == 0) {
        part_s[mt * 16 + rowb + r][wave] = s;
        part_q[mt * 16 + rowb + r][wave] = q;
      }
    }
  __syncthreads();

  if (tid < BM2) {
    float s = part_s[tid][0] + part_s[tid][1] + part_s[tid][2] + part_s[tid][3];
    float q = part_q[tid][0] + part_q[tid][1] + part_q[tid][2] + part_q[tid][3];
    float mu = s * (1.f / H);
    mu_s[tid] = mu;
    rs_s[tid] = rsqrtf(q * (1.f / H) - mu * mu + 1e-5f);
  }
  __syncthreads();

#pragma unroll
  for (int t = 0; t < 2; ++t) {
    const int col = (wave * 2 + t) * 16 + fr;
    const float g = g2[col], b = bt2[col];
#pragma unroll
    for (int mt = 0; mt < 2; ++mt) {
#pragma unroll
      for (int r = 0; r < 4; ++r) {
        const int row = mt * 16 + rowb + r;
        const float xv = x_val[(row0 + row) * H + col];
        out[(row0 + row) * H + col] = (d[mt][t][r] - mu_s[row]) * rs_s[row] * g + b + xv;
      }
    }
  }
}

// ---------------------------------------------------------------- fp32 fallback MLPs
__global__ __launch_bounds__(256) void cst_mlp_kernel(
    const float* __restrict__ r_cst,
    const float* __restrict__ W1, const float* __restrict__ b1,
    const float* __restrict__ W2, const float* __restrict__ g1,
    const float* __restrict__ bt1, float* __restrict__ m) {
  __shared__ float As[BM][H];
  __shared__ float Cs[BM][H];
  __shared__ float Ds[BM][H4];
  __shared__ float mu_s[BM], rs_s[BM];
  const int tid = threadIdx.x;
  const long row0 = (long)blockIdx.x * BM;
  {
    const float4* src = (const float4*)(r_cst + row0 * H);
    float4* dst = (float4*)&As[0][0];
#pragma unroll
    for (int i = 0; i < 2; ++i) dst[tid + i * 256] = src[tid + i * 256];
  }
  __syncthreads();
  {
    const int j = tid & (H - 1);
    const int r0 = (tid >> 7) * 8;
    float acc[8] = {0, 0, 0, 0, 0, 0, 0, 0};
#pragma unroll 4
    for (int k = 0; k < H; ++k) {
      float w = W1[k * H + j];
#pragma unroll
      for (int r = 0; r < 8; ++r) acc[r] = fmaf(As[r0 + r][k], w, acc[r]);
    }
    float bb = b1[j];
#pragma unroll
    for (int r = 0; r < 8; ++r) Cs[r0 + r][j] = fmaxf(acc[r] + bb, 0.f);
  }
  __syncthreads();
  {
    const int j = tid * 2;
    float acc[BM][2];
#pragma unroll
    for (int r = 0; r < BM; ++r) acc[r][0] = acc[r][1] = 0.f;
    for (int k = 0; k < H; k += 4) {
      float4 c[BM];
#pragma unroll
      for (int r = 0; r < BM; ++r) c[r] = *(const float4*)&Cs[r][k];
#pragma unroll
      for (int kk = 0; kk < 4; ++kk) {
        const float2 w = *(const float2*)&W2[(k + kk) * H4 + j];
#pragma unroll
        for (int r = 0; r < BM; ++r) {
          float cv = (&c[r].x)[kk];
          acc[r][0] = fmaf(cv, w.x, acc[r][0]);
          acc[r][1] = fmaf(cv, w.y, acc[r][1]);
        }
      }
    }
#pragma unroll
    for (int r = 0; r < BM; ++r) {
      Ds[r][j] = acc[r][0];
      Ds[r][j + 1] = acc[r][1];
    }
  }
  __syncthreads();
  {
    const int wv = tid >> 6, lane = tid & 63;
    for (int r = wv * 4; r < wv * 4 + 4; ++r) {
      float s = 0.f, q = 0.f;
      const float4* rowp = (const float4*)&Ds[r][0];
#pragma unroll
      for (int i = 0; i < 2; ++i) {
        float4 v = rowp[lane * 2 + i];
        s += v.x + v.y + v.z + v.w;
        q += v.x * v.x + v.y * v.y + v.z * v.z + v.w * v.w;
      }
#pragma unroll
      for (int off = 32; off; off >>= 1) {
        s += __shfl_xor(s, off);
        q += __shfl_xor(q, off);
      }
      if (lane == 0) {
        float mu = s * (1.f / H4);
        mu_s[r] = mu;
        rs_s[r] = rsqrtf(q * (1.f / H4) - mu * mu + 1e-5f);
      }
    }
  }
  __syncthreads();
  {
    float4* out4 = (float4*)(m + row0 * H4);
    const float4* D4 = (const float4*)&Ds[0][0];
    const float4* g4 = (const float4*)g1;
    const float4* b4 = (const float4*)bt1;
#pragma unroll
    for (int it = 0; it < 8; ++it) {
      int e4 = tid + it * 256;
      int r = e4 >> 7;
      int c4 = e4 & 127;
      float4 v = D4[e4];
      float4 g = g4[c4], b = b4[c4];
      float mu = mu_s[r], rs = rs_s[r];
      float4 o;
      o.x = (v.x - mu) * rs * g.x + b.x;
      o.y = (v.y - mu) * rs * g.y + b.y;
      o.z = (v.z - mu) * rs * g.z + b.z;
      o.w = (v.w - mu) * rs * g.w + b.w;
      out4[e4] = o;
    }
  }
}

__global__ __launch_bounds__(256) void val_mlp_kernel(
    const float* h, const float* __restrict__ x_val,
    const float* __restrict__ W3, const float* __restrict__ b3,
    const float* __restrict__ W4, const float* __restrict__ g2,
    const float* __restrict__ bt2, float* out) {
  __shared__ float As[BM][H];
  __shared__ float Cs[BM][H];
  __shared__ float Ds[BM][H];
  __shared__ float mu_s[BM], rs_s[BM];
  const int tid = threadIdx.x;
  const long row0 = (long)blockIdx.x * BM;
  {
    const float4* src = (const float4*)(h + row0 * H);
    float4* dst = (float4*)&As[0][0];
#pragma unroll
    for (int i = 0; i < 2; ++i) dst[tid + i * 256] = src[tid + i * 256];
  }
  __syncthreads();
  const int j = tid & (H - 1);
  const int r0 = (tid >> 7) * 8;
  {
    float acc[8] = {0, 0, 0, 0, 0, 0, 0, 0};
#pragma unroll 4
    for (int k = 0; k < H; ++k) {
      float w = W3[k * H + j];
#pragma unroll
      for (int r = 0; r < 8; ++r) acc[r] = fmaf(As[r0 + r][k], w, acc[r]);
    }
    float bb = b3[j];
#pragma unroll
    for (int r = 0; r < 8; ++r) Cs[r0 + r][j] = fmaxf(acc[r] + bb, 0.f);
  }
  __syncthreads();
  {
    float acc[8] = {0, 0, 0, 0, 0, 0, 0, 0};
#pragma unroll 4
    for (int k = 0; k < H; ++k) {
      float w = W4[k * H + j];
#pragma unroll
      for (int r = 0; r < 8; ++r) acc[r] = fmaf(Cs[r0 + r][k], w, acc[r]);
    }
#pragma unroll
    for (int r = 0; r < 8; ++r) Ds[r0 + r][j] = acc[r];
  }
  __syncthreads();
  {
    const int wv = tid >> 6, lane = tid & 63;
    for (int r = wv * 4; r < wv * 4 + 4; ++r) {
      float2 v = *(const float2*)&Ds[r][lane * 2];
      float s = v.x + v.y, q = v.x * v.x + v.y * v.y;
#pragma unroll
      for (int off = 32; off; off >>= 1) {
        s += __shfl_xor(s, off);
        q += __shfl_xor(q, off);
      }
      if (lane == 0) {
        float mu = s * (1.f / H);
        mu_s[r] = mu;
        rs_s[r] = rsqrtf(q * (1.f / H) - mu * mu + 1e-5f);
      }
    }
  }
  __syncthreads();
  {
    float4* out4 = (float4*)(out + row0 * H);
    const float4* x4 = (const float4*)(x_val + row0 * H);
    const float4* D4 = (const float4*)&Ds[0][0];
    const float4* g4 = (const float4*)g2;
    const float4* b4 = (const float4*)bt2;
#pragma unroll
    for (int it = 0; it < 2; ++it) {
      int e4 = tid + it * 256;
      int r = e4 >> 5;
      int c4 = e4 & 31;
      float4 v = D4[e4];
      float4 g = g4[c4], b = b4[c4], xv = x4[e4];
      float mu = mu_s[r], rs = rs_s[r];
      float4 o;
      o.x = (v.x - mu) * rs * g.x + b.x + xv.x;
      o.y = (v.y - mu) * rs * g.y + b.y + xv.y;
      o.z = (v.z - mu) * rs * g.z + b.z + xv.z;
      o.w = (v.w - mu) * rs * g.w + b.w + xv.w;
      out4[e4] = o;
    }
  }
}

// ---------------------------------------------------------------- CSR build
__global__ __launch_bounds__(256) void count_kernel(const int* __restrict__ e_in,
                                                    int* __restrict__ cnt, int nE) {
  int i = blockIdx.x * 256 + threadIdx.x;
  if (i < nE) atomicAdd(&cnt[e_in[i]], 1);
}

__device__ inline int wave_incl_scan(int x) {
#pragma unroll
  for (int off = 1; off < 64; off <<= 1) {
    int y = __shfl_up(x, off);
    if ((threadIdx.x & 63) >= off) x += y;
  }
  return x;
}

__global__ __launch_bounds__(256) void scan1_kernel(const int* __restrict__ cnt,
                                                    int* __restrict__ offs,
                                                    int* __restrict__ bsums, int n) {
  int i = blockIdx.x * 256 + threadIdx.x;
  int v = (i < n) ? cnt[i] : 0;
  int incl = wave_incl_scan(v);
  __shared__ int wsum[4];
  int wv = threadIdx.x >> 6, lane = threadIdx.x & 63;
  if (lane == 63) wsum[wv] = incl;
  __syncthreads();
  int add = 0;
  for (int w = 0; w < wv; ++w) add += wsum[w];
  if (i < n) offs[i] = incl - v + add;
  if (threadIdx.x == 255) bsums[blockIdx.x] = incl + add;
}

__global__ __launch_bounds__(1024) void scan2_kernel(int* __restrict__ bsums, int nb,
                                                     int* __restrict__ offs, int n, int total) {
  __shared__ int s[1024];
  int t = threadIdx.x;
  int orig = (t < nb) ? bsums[t] : 0;
  s[t] = orig;
  __syncthreads();
  for (int off = 1; off < 1024; off <<= 1) {
    int v = (t >= off) ? s[t - off] : 0;
    __syncthreads();
    s[t] += v;
    __syncthreads();
  }
  if (t < nb) bsums[t] = s[t] - orig;
  if (t == 0) offs[n] = total;
}

__global__ __launch_bounds__(256) void scan3_kernel(int* __restrict__ offs,
                                                    const int* __restrict__ bsums, int n) {
  int i = blockIdx.x * 256 + threadIdx.x;
  if (i < n) offs[i] += bsums[blockIdx.x];
}

__global__ __launch_bounds__(256) void fill_kernel(
    const int* __restrict__ e_out, const int* __restrict__ e_in,
    const int* __restrict__ LE, const int* __restrict__ PE,
    const int* __restrict__ offs, int* __restrict__ cnt2,
    int* __restrict__ msg_row, int nE) {
  int e = blockIdx.x * 256 + threadIdx.x;
  if (e >= nE) return;
  int v = e_in[e];
  int pos = offs[v] + atomicAdd(&cnt2[v], 1);
  msg_row[pos] = 4 * e_out[e] + 2 * LE[e] + PE[e];
}

// ---------------------------------------------------------------- gather-reduce (fp16 m): h = x_val + sum(msgs)
// one wave per value row; two half-waves, 4 cols/lane (half4 = 8B), interleaved msg indices.
__global__ __launch_bounds__(256) void gather_h_kernel(
    const _Float16* __restrict__ m, const float* __restrict__ x_val,
    const int* __restrict__ offs, const int* __restrict__ msg_row,
    float* __restrict__ h, int nv) {
  int v = blockIdx.x * 4 + (threadIdx.x >> 6);
  if (v >= nv) return;
  int lane = threadIdx.x & 63;
  int half = lane >> 5, li = lane & 31;
  int beg = offs[v], end = offs[v + 1];
  float4 acc = {0.f, 0.f, 0.f, 0.f};
  int p = beg + half;
  for (; p + 2 < end; p += 4) {
    int r0 = msg_row[p];
    int r1 = msg_row[p + 2];
    half4 a = *(const half4*)(m + (long)r0 * H + li * 4);
    half4 b = *(const half4*)(m + (long)r1 * H + li * 4);
    acc.x += (float)a.x + (float)b.x;
    acc.y += (float)a.y + (float)b.y;
    acc.z += (float)a.z + (float)b.z;
    acc.w += (float)a.w + (float)b.w;
  }
  if (p < end) {
    int r0 = msg_row[p];
    half4 a = *(const half4*)(m + (long)r0 * H + li * 4);
    acc.x += (float)a.x;
    acc.y += (float)a.y;
    acc.z += (float)a.z;
    acc.w += (float)a.w;
  }
  acc.x += __shfl_xor(acc.x, 32);
  acc.y += __shfl_xor(acc.y, 32);
  acc.z += __shfl_xor(acc.z, 32);
  acc.w += __shfl_xor(acc.w, 32);
  if (half == 0) {
    float4 xv = *(const float4*)(x_val + (long)v * H + li * 4);
    acc.x += xv.x;
    acc.y += xv.y;
    acc.z += xv.z;
    acc.w += xv.w;
    *(float4*)(h + (long)v * H + li * 4) = acc;
  }
}

// ---------------------------------------------------------------- fp32 gather (fallback pairing with fp32 cst)
__global__ __launch_bounds__(256) void gather_kernel(
    const float* __restrict__ m, const float* __restrict__ x_val,
    const int* __restrict__ offs, const int* __restrict__ msg_row,
    float* __restrict__ h, int nv) {
  int v = blockIdx.x * 4 + (threadIdx.x >> 6);
  if (v >= nv) return;
  int lane = threadIdx.x & 63;
  int half = lane >> 5, li = lane & 31;
  int beg = offs[v], end = offs[v + 1];
  float4 acc = {0.f, 0.f, 0.f, 0.f};
  int p = beg + half;
  for (; p + 2 < end; p += 4) {
    int r0 = msg_row[p];
    int r1 = msg_row[p + 2];
    float4 a = *(const float4*)(m + (long)r0 * H + li * 4);
    float4 b = *(const float4*)(m + (long)r1 * H + li * 4);
    acc.x += a.x + b.x;
    acc.y += a.y + b.y;
    acc.z += a.z + b.z;
    acc.w += a.w + b.w;
  }
  if (p < end) {
    int r0 = msg_row[p];
    float4 a = *(const float4*)(m + (long)r0 * H + li * 4);
    acc.x += a.x;
    acc.y += a.y;
    acc.z += a.z;
    acc.w += a.w;
  }
  acc.x += __shfl_xor(acc.x, 32);
  acc.y += __shfl_xor(acc.y, 32);
  acc.z += __shfl_xor(acc.z, 32);
  acc.w += __shfl_xor(acc.w, 32);
  if (half == 0) {
    float4 xv = *(const float4*)(x_val + (long)v * H + li * 4);
    acc.x += xv.x;
    acc.y += xv.y;
    acc.z += xv.z;
    acc.w += xv.w;
    *(float4*)(h + (long)v * H + li * 4) = acc;
  }
}

// ---------------------------------------------------------------- fallback atomic scatter (fp32 m)
__global__ __launch_bounds__(256) void scatter_kernel(
    const float* __restrict__ m, const int* __restrict__ e_out,
    const int* __restrict__ e_in, const int* __restrict__ LE,
    const int* __restrict__ PE, float* h, int nE) {
  int t = blockIdx.x * 256 + threadIdx.x;
  int edge = t >> 5;
  if (edge >= nE) return;
  int lane = t & 31;
  int c0 = e_out[edge];
  int c1 = e_in[edge];
  int oi = 4 * c0 + 2 * LE[edge] + PE[edge];
  float4 v = *(const float4*)(m + (long)oi * H + lane * 4);
  float* dst = h + (long)c1 * H + lane * 4;
  unsafeAtomicAdd(dst + 0, v.x);
  unsafeAtomicAdd(dst + 1, v.y);
  unsafeAtomicAdd(dst + 2, v.z);
  unsafeAtomicAdd(dst + 3, v.w);
}

extern "C" void kernel_launch(void* const* d_in, const int* in_sizes, int n_in,
                              void* d_out, int out_size, void* d_ws, size_t ws_size,
                              hipStream_t stream) {
  const float* x_val = (const float*)d_in[0];
  const float* r_cst = (const float*)d_in[1];
  const int* edges  = (const int*)d_in[2];   // [2, E]
  const int* LE     = (const int*)d_in[3];
  const int* PE     = (const int*)d_in[4];
  const float* W1  = (const float*)d_in[7];
  const float* b1  = (const float*)d_in[8];
  const float* W2  = (const float*)d_in[9];
  const float* g1  = (const float*)d_in[10];
  const float* bt1 = (const float*)d_in[11];
  const float* W3  = (const float*)d_in[12];
  const float* b3  = (const float*)d_in[13];
  const float* W4  = (const float*)d_in[14];
  const float* g2  = (const float*)d_in[15];
  const float* bt2 = (const float*)d_in[16];

  const int NV = in_sizes[0] / H;
  const int NC = in_sizes[1] / H;
  const int nE = in_sizes[3];

  float* out  = (float*)d_out;
  float* mbuf = (float*)d_ws;             // fp32 m (fallback)
  _Float16* mbuf_h = (_Float16*)d_ws;     // fp16 m (MFMA path)

  const size_t mbytes = (size_t)4 * NC * H * sizeof(float);  // reserve fp32 size either way
  int* offs  = (int*)((char*)d_ws + mbytes);          // NV+1
  int* cnt   = offs + (NV + 1);                       // NV
  int* cnt2  = cnt + NV;                              // NV
  int* bsums = cnt2 + NV;                             // up to 1024
  int* msg_row = bsums + 1024;                        // nE
  const size_t csr_bytes = ((size_t)(NV + 1) + NV + NV + 1024 + nE) * sizeof(int);
  const size_t need_csr = mbytes + csr_bytes;

  // weight packs (hi/lo bf16 fragments) after CSR arrays, 64B aligned
  const size_t pack_off = (need_csr + 63) & ~(size_t)63;
  __bf16* W1h = (__bf16*)((char*)d_ws + pack_off);
  __bf16* W1l = W1h + 16384;
  __bf16* W2h = W1l + 16384;
  __bf16* W2l = W2h + 65536;
  __bf16* W3h = W2l + 65536;
  __bf16* W3l = W3h + 16384;
  __bf16* W4h = W3l + 16384;
  __bf16* W4l = W4h + 16384;
  const size_t need_mfma = pack_off + (size_t)(2 * (16384 * 3 + 65536)) * sizeof(__bf16);

  const int nb = (NV + 255) / 256;
  const bool csr_ok = (ws_size >= need_csr) && (nb <= 1024);
  const bool mfma_ok = csr_ok && (ws_size >= need_mfma) && (NC % BM2 == 0) && (NV % BM2 == 0);

  if (mfma_ok) {
    pack_kernel<<<8, 256, 0, stream>>>(W1, H, H, W1h, W1l);
    pack_kernel<<<32, 256, 0, stream>>>(W2, H, H4, W2h, W2l);
    pack_kernel<<<8, 256, 0, stream>>>(W3, H, H, W3h, W3l);
    pack_kernel<<<8, 256, 0, stream>>>(W4, H, H, W4h, W4l);
    cst_mlp_mfma<<<NC / BM2, 256, 0, stream>>>(r_cst, W1h, W1l, b1, W2h, W2l, g1, bt1, mbuf_h);
  } else {
    cst_mlp_kernel<<<NC / BM, 256, 0, stream>>>(r_cst, W1, b1, W2, g1, bt1, mbuf);
  }

  if (csr_ok) {
    hipMemsetAsync(cnt, 0, (size_t)NV * sizeof(int), stream);
    hipMemsetAsync(cnt2, 0, (size_t)NV * sizeof(int), stream);
    count_kernel<<<(nE + 255) / 256, 256, 0, stream>>>(edges + nE, cnt, nE);
    scan1_kernel<<<nb, 256, 0, stream>>>(cnt, offs, bsums, NV);
    scan2_kernel<<<1, 1024, 0, stream>>>(bsums, nb, offs, NV, nE);
    scan3_kernel<<<nb, 256, 0, stream>>>(offs, bsums, NV);
    fill_kernel<<<(nE + 255) / 256, 256, 0, stream>>>(edges, edges + nE, LE, PE, offs, cnt2,
                                                      msg_row, nE);
    if (mfma_ok) {
      gather_h_kernel<<<(NV + 3) / 4, 256, 0, stream>>>(mbuf_h, x_val, offs, msg_row, out, NV);
    } else {
      gather_kernel<<<(NV + 3) / 4, 256, 0, stream>>>(mbuf, x_val, offs, msg_row, out, NV);
    }
  } else {
    copy_kernel<<<2048, 256, 0, stream>>>((const float4*)x_val, (float4*)out, NV * H / 4);
    scatter_kernel<<<(nE * 32 + 255) / 256, 256, 0, stream>>>(mbuf, edges, edges + nE, LE, PE,
                                                              out, nE);
  }

  if (mfma_ok) {
    val_mlp_mfma<<<NV / BM2, 256, 0, stream>>>(out, x_val, W3h, W3l, b3, W4h, W4l, g2, bt2, out);
  } else {
    val_mlp_kernel<<<NV / BM, 256, 0, stream>>>(out, x_val, W3, b3, W4, g2, bt2, out);
  }
}